// Round 10
// baseline (222.808 us; speedup 1.0000x reference)
//
#include <hip/hip_runtime.h>
#include <math.h>

#define NN 512
#define NN2 (NN*NN)
#define NB 32
#define NM 64

typedef __attribute__((ext_vector_type(8))) short short8v;   // 8 bf16 (4 VGPR)
typedef __attribute__((ext_vector_type(4))) float f32x4;     // MFMA acc

__device__ __forceinline__ float sigm(float x) { return 1.0f / (1.0f + expf(-x)); }

__device__ __forceinline__ unsigned short f2bf(float x) {
  unsigned u = __float_as_uint(x);
  return (unsigned short)((u + 0x7fffu + ((u >> 16) & 1u)) >> 16);   // RNE
}
__device__ __forceinline__ float bf2f(unsigned short h) {
  return __uint_as_float(((unsigned)h) << 16);
}
__device__ __forceinline__ unsigned long long u64min(unsigned long long a,
                                                     unsigned long long b) {
  return (b < a) ? b : a;
}
__device__ __forceinline__ void amin64(unsigned long long* p, unsigned long long v) {
  unsigned long long old = *p;
  while (v < old) {
    unsigned long long assumed = old;
    old = atomicCAS(p, assumed, v);
    if (old == assumed) break;
  }
}
template <int CTRL>
__device__ __forceinline__ unsigned long long dpp_min_u64(unsigned long long x) {
  int xlo = (int)(unsigned)x, xhi = (int)(unsigned)(x >> 32);
  int ylo = __builtin_amdgcn_update_dpp(xlo, xlo, CTRL, 0xf, 0xf, false);
  int yhi = __builtin_amdgcn_update_dpp(xhi, xhi, CTRL, 0xf, 0xf, false);
  unsigned long long y = ((unsigned long long)(unsigned)yhi << 32) | (unsigned)ylo;
  return (y < x) ? y : x;
}
__device__ __forceinline__ unsigned long long wave_min_u64(unsigned long long k) {
  k = dpp_min_u64<0x111>(k); k = dpp_min_u64<0x112>(k);
  k = dpp_min_u64<0x114>(k); k = dpp_min_u64<0x118>(k);
  k = dpp_min_u64<0x142>(k); k = dpp_min_u64<0x143>(k);
  return k;
}
__device__ __forceinline__ unsigned long long grp16_min_u64(unsigned long long k) {
  k = dpp_min_u64<0x111>(k); k = dpp_min_u64<0x112>(k);
  k = dpp_min_u64<0x114>(k); k = dpp_min_u64<0x118>(k);
  return k;
}

// -------- sigmoid + bf16 hi/lo split + fused row sums-of-squares ----------------
__global__ __launch_bounds__(256) void split_kernel(const float* __restrict__ model,
                                                    const float* __restrict__ labels,
                                                    unsigned short* __restrict__ Hi,
                                                    unsigned short* __restrict__ Lo,
                                                    float* __restrict__ sq, int m0) {
  int b = blockIdx.x;
  int mL = b >> 8;
  int m = m0 + mL;
  int tid = threadIdx.x;
  size_t off = (size_t)(b & 255) * 1024 + tid * 4;
  const float* src = ((m & 1) ? labels + (size_t)(m >> 1) * NN2
                              : model + (size_t)(m >> 1) * NN2) + off;
  float4 v = *(const float4*)src;
  if (!(m & 1)) { v.x = sigm(v.x); v.y = sigm(v.y); v.z = sigm(v.z); v.w = sigm(v.w); }
  ushort4 h, l;
  h.x = f2bf(v.x); l.x = f2bf(v.x - bf2f(h.x));
  h.y = f2bf(v.y); l.y = f2bf(v.y - bf2f(h.y));
  h.z = f2bf(v.z); l.z = f2bf(v.z - bf2f(h.z));
  h.w = f2bf(v.w); l.w = f2bf(v.w - bf2f(h.w));
  *(ushort4*)(Hi + (size_t)mL * NN2 + off) = h;
  *(ushort4*)(Lo + (size_t)mL * NN2 + off) = l;
  float s = v.x * v.x + v.y * v.y + v.z * v.z + v.w * v.w;
  #pragma unroll
  for (int o = 32; o > 0; o >>= 1) s += __shfl_down(s, o);
  __shared__ float red[4];
  if ((tid & 63) == 0) red[tid >> 6] = s;
  __syncthreads();
  if (tid == 0) {
    int row0 = (b & 255) * 2;
    sq[(size_t)m * NN + row0]     = red[0] + red[1];
    sq[(size_t)m * NN + row0 + 1] = red[2] + red[3];
  }
}

// ------- distance matrix: LDS-free 3-pass split-bf16 MFMA (direct global frags) -
__global__ __launch_bounds__(256) void gemm_dist(const unsigned short* __restrict__ Hi,
                                                 const unsigned short* __restrict__ Lo,
                                                 const float* __restrict__ sq,
                                                 float* __restrict__ Dreg,
                                                 unsigned* __restrict__ maxBits,
                                                 unsigned long long* __restrict__ best1,
                                                 int m0, int nm) {
  // XCD-aware decode: blocks of one matrix land on one XCD (id%8 = XCD)
  int id = blockIdx.x;
  int p, mL;
  if ((nm & 7) == 0) {
    int x = id & 7, t = id >> 3;
    p = t % 10;
    mL = x + 8 * (t / 10);
  } else {
    p = id % 10;
    mL = id / 10;
  }
  int by = (p >= 4) + (p >= 7) + (p >= 9);
  int bx = p - ((by * (7 - by)) >> 1);
  bool diag = (by == bx);
  int m = m0 + mL;
  const unsigned short* Hm = Hi + (size_t)mL * NN2;
  const unsigned short* Lm = Lo + (size_t)mL * NN2;

  int tid = threadIdx.x;
  int wid = tid >> 6, lane = tid & 63;
  int wy = wid >> 1, wx = wid & 1;    // 2x2 waves of 64x64
  int lr = lane & 15, lk = lane >> 4;

  // direct global fragment bases: lane frag = 8 contiguous bf16 at
  // [panel_row0 + mi*16 + lr][k0 + lk*8]
  const unsigned short* gAh = Hm + (size_t)(by * 128 + wy * 64 + lr) * NN + lk * 8;
  const unsigned short* gAl = Lm + (size_t)(by * 128 + wy * 64 + lr) * NN + lk * 8;
  const unsigned short* gBh = Hm + (size_t)(bx * 128 + wx * 64 + lr) * NN + lk * 8;
  const unsigned short* gBl = Lm + (size_t)(bx * 128 + wx * 64 + lr) * NN + lk * 8;

  f32x4 acc[4][4];
  #pragma unroll
  for (int i = 0; i < 4; ++i)
    #pragma unroll
    for (int j = 0; j < 4; ++j) acc[i][j] = (f32x4){0.f, 0.f, 0.f, 0.f};

  for (int s = 0; s < 16; ++s) {
    int k0 = s * 32;
    short8v avh[4], avl[4], bvh[4], bvl[4];
    #pragma unroll
    for (int i = 0; i < 4; ++i) {
      avh[i] = *(const short8v*)(gAh + (size_t)(i * 16) * NN + k0);
      avl[i] = *(const short8v*)(gAl + (size_t)(i * 16) * NN + k0);
      bvh[i] = *(const short8v*)(gBh + (size_t)(i * 16) * NN + k0);
      bvl[i] = *(const short8v*)(gBl + (size_t)(i * 16) * NN + k0);
    }
    #pragma unroll
    for (int mi = 0; mi < 4; ++mi)
      #pragma unroll
      for (int ni = 0; ni < 4; ++ni)
        acc[mi][ni] = __builtin_amdgcn_mfma_f32_16x16x32_bf16(avh[mi], bvh[ni], acc[mi][ni], 0, 0, 0);
    #pragma unroll
    for (int mi = 0; mi < 4; ++mi)
      #pragma unroll
      for (int ni = 0; ni < 4; ++ni)
        acc[mi][ni] = __builtin_amdgcn_mfma_f32_16x16x32_bf16(avh[mi], bvl[ni], acc[mi][ni], 0, 0, 0);
    #pragma unroll
    for (int mi = 0; mi < 4; ++mi)
      #pragma unroll
      for (int ni = 0; ni < 4; ++ni)
        acc[mi][ni] = __builtin_amdgcn_mfma_f32_16x16x32_bf16(avl[mi], bvh[ni], acc[mi][ni], 0, 0, 0);
  }

  const float* sqm = sq + (size_t)m * NN;
  float* Dm = Dreg + (size_t)mL * NN2;
  int gr0 = by * 128 + wy * 64;
  int gc0 = bx * 128 + wx * 64;
  float tmax = 0.f;
  unsigned long long rk[4][4];
  unsigned long long ck[4];
  #pragma unroll
  for (int i = 0; i < 4; ++i) {
    ck[i] = ~0ull;
    #pragma unroll
    for (int j = 0; j < 4; ++j) rk[i][j] = ~0ull;
  }
  #pragma unroll
  for (int mi = 0; mi < 4; ++mi) {
    int rb = gr0 + mi * 16 + lk * 4;
    float sqi0 = sqm[rb + 0], sqi1 = sqm[rb + 1], sqi2 = sqm[rb + 2], sqi3 = sqm[rb + 3];
    #pragma unroll
    for (int ni = 0; ni < 4; ++ni) {
      int col = gc0 + ni * 16 + lr;
      float sqj = sqm[col];
      f32x4 a = acc[mi][ni];
      float v0 = sqrtf(fmaxf(sqi0 + sqj - 2.f * a[0], 0.f));
      float v1 = sqrtf(fmaxf(sqi1 + sqj - 2.f * a[1], 0.f));
      float v2 = sqrtf(fmaxf(sqi2 + sqj - 2.f * a[2], 0.f));
      float v3 = sqrtf(fmaxf(sqi3 + sqj - 2.f * a[3], 0.f));
      Dm[(size_t)(rb + 0) * NN + col] = v0;
      Dm[(size_t)(rb + 1) * NN + col] = v1;
      Dm[(size_t)(rb + 2) * NN + col] = v2;
      Dm[(size_t)(rb + 3) * NN + col] = v3;
      if (!diag)
        *(float4*)(Dm + (size_t)col * NN + rb) = make_float4(v0, v1, v2, v3);
      tmax = fmaxf(tmax, fmaxf(fmaxf(v0, v1), fmaxf(v2, v3)));
      float vv[4] = {v0, v1, v2, v3};
      #pragma unroll
      for (int rg = 0; rg < 4; ++rg) {
        int row = rb + rg;
        if (!diag || col != row) {
          unsigned lo = (row < col) ? (unsigned)(row * NN + col)
                                    : (unsigned)(col * NN + row);
          unsigned long long key =
              ((unsigned long long)__float_as_uint(vv[rg]) << 32) | lo;
          rk[mi][rg] = u64min(rk[mi][rg], key);
          ck[ni] = u64min(ck[ni], key);
        }
      }
    }
  }
  unsigned long long* b1 = best1 + (size_t)m * NN;
  #pragma unroll
  for (int mi = 0; mi < 4; ++mi)
    #pragma unroll
    for (int rg = 0; rg < 4; ++rg) {
      unsigned long long k = grp16_min_u64(rk[mi][rg]);
      if (lr == 15) atomicMin(&b1[gr0 + mi * 16 + lk * 4 + rg], k);
    }
  if (!diag) {
    #pragma unroll
    for (int ni = 0; ni < 4; ++ni) {
      unsigned long long k = ck[ni];
      k = u64min(k, __shfl_xor(k, 16));
      k = u64min(k, __shfl_xor(k, 32));
      if (lk == 0) atomicMin(&b1[gc0 + ni * 16 + lr], k);
    }
  }
  #pragma unroll
  for (int off = 32; off > 0; off >>= 1) tmax = fmaxf(tmax, __shfl_down(tmax, off));
  if (lane == 0) atomicMax(&maxBits[m], __float_as_uint(tmax));
}

// -------- phase-1 hook (comp = identity), emit edges, write comp labels ---------
__global__ __launch_bounds__(512) void hook1_kernel(const unsigned long long* __restrict__ best1,
                                                    int* __restrict__ compG,
                                                    int2* __restrict__ eo_all,
                                                    int* __restrict__ ecntG, int m0) {
  int mL = blockIdx.x, m = m0 + mL;
  const unsigned long long* b1 = best1 + (size_t)m * NN;
  int2* eo = eo_all + (size_t)m * (NN - 1);
  __shared__ int hook[NN], parent[NN];
  __shared__ int ecnt;
  int tid = threadIdx.x;
  if (tid == 0) ecnt = 0;
  unsigned long long b = b1[tid];
  int h;
  if (b != ~0ull) {
    int idx = (int)(unsigned)b;
    int er = idx >> 9, ec = idx & 511;
    h = (er == tid) ? ec : er;
  } else h = tid;
  hook[tid] = h;
  __syncthreads();
  bool active = (b != ~0ull);
  int p = h;
  bool mutual = active && (hook[p] == tid);
  parent[tid] = (!active) ? tid : ((mutual && tid < p) ? tid : p);
  if (active && (!mutual || tid > p)) {
    int idx = (int)(unsigned)b;
    int e = atomicAdd(&ecnt, 1);
    eo[e] = make_int2(idx >> 9, idx & 511);
  }
  __syncthreads();
  int c = tid, pp = parent[c];
  while (pp != c) { c = pp; pp = parent[c]; }
  compG[(size_t)m * NN + tid] = c;
  if (tid == 0) ecntG[m] = ecnt;
}

// -------- phase-2 scan: 8 blocks/matrix, wave-per-row, atomicMin per comp -------
__global__ __launch_bounds__(512) void scan2_kernel(const float* __restrict__ Dreg,
                                                    const int* __restrict__ compG,
                                                    unsigned long long* __restrict__ best2,
                                                    int m0) {
  int sblk = blockIdx.x, mL = blockIdx.y, m = m0 + mL;
  const float* D = Dreg + (size_t)mL * NN2;
  __shared__ int compP[NN + 64];
  int tid = threadIdx.x;
  int wave = tid >> 6, lane = tid & 63;
  int c0 = lane * 8;
  if (tid < NN) compP[tid + (tid >> 3)] = compG[(size_t)m * NN + tid];
  __syncthreads();
  unsigned long long* b2 = best2 + (size_t)m * NN;
  #pragma unroll
  for (int rr = 0; rr < 8; ++rr) {
    int r = sblk * 64 + wave * 8 + rr;
    int cr = compP[r + (r >> 3)];
    const float4* rp = (const float4*)(D + (size_t)r * NN + c0);
    float4 v0 = rp[0], v1 = rp[1];
    int4 cc0 = *(const int4*)(compP + c0 + (c0 >> 3));
    int4 cc1 = *(const int4*)(compP + c0 + 4 + (c0 >> 3));
    float vv[8] = {v0.x, v0.y, v0.z, v0.w, v1.x, v1.y, v1.z, v1.w};
    int cv[8] = {cc0.x, cc0.y, cc0.z, cc0.w, cc1.x, cc1.y, cc1.z, cc1.w};
    unsigned long long k = ~0ull;
    #pragma unroll
    for (int e = 0; e < 8; ++e) {
      if (cv[e] != cr) {
        int col = c0 + e;
        int lo = (r < col) ? r * NN + col : col * NN + r;
        unsigned long long key = ((unsigned long long)__float_as_uint(vv[e]) << 32) | (unsigned)lo;
        k = u64min(k, key);
      }
    }
    k = wave_min_u64(k);
    if (lane == 63 && k != ~0ull) atomicMin(&b2[cr], k);
  }
}

// -------- phase-2 hook + dense remap (C <= 128 guaranteed) ----------------------
__global__ __launch_bounds__(512) void hook2_kernel(const unsigned long long* __restrict__ best2,
                                                    const int* __restrict__ compG,
                                                    int* __restrict__ comp2g,
                                                    int2* __restrict__ eo_all,
                                                    int* __restrict__ ecntG,
                                                    int* __restrict__ cntG, int m0) {
  int mL = blockIdx.x, m = m0 + mL;
  const unsigned long long* b2 = best2 + (size_t)m * NN;
  int2* eo = eo_all + (size_t)m * (NN - 1);
  __shared__ int comp[NN], hook[NN], parent[NN], dmap[NN];
  __shared__ int ecnt, ccnt;
  int tid = threadIdx.x;
  if (tid == 0) { ecnt = ecntG[m]; ccnt = 0; }
  comp[tid] = compG[(size_t)m * NN + tid];
  __syncthreads();
  unsigned long long b = b2[tid];
  int h;
  if (b != ~0ull) {
    int idx = (int)(unsigned)b;
    int er = idx >> 9, ec = idx & 511;
    int c1 = comp[er], c2 = comp[ec];
    h = (c1 == tid) ? c2 : c1;
  } else h = tid;
  hook[tid] = h;
  __syncthreads();
  bool active = (b != ~0ull);
  int p = h;
  bool mutual = active && (hook[p] == tid);
  parent[tid] = (!active) ? tid : ((mutual && tid < p) ? tid : p);
  if (active && (!mutual || tid > p)) {
    int idx = (int)(unsigned)b;
    int e = atomicAdd(&ecnt, 1);
    eo[e] = make_int2(idx >> 9, idx & 511);
  }
  __syncthreads();
  int c = comp[tid], pp = parent[c];
  while (pp != c) { c = pp; pp = parent[c]; }
  __syncthreads();
  comp[tid] = c;
  __syncthreads();
  if (comp[tid] == tid) dmap[tid] = atomicAdd(&ccnt, 1);
  __syncthreads();
  comp2g[(size_t)m * NN + tid] = dmap[comp[tid]];
  if (tid == 0) { ecntG[m] = ecnt; cntG[m] = ccnt; }
}

// -------- contraction: 4 blocks/matrix build LDS-partial Dc, merge to global ----
__global__ __launch_bounds__(512) void contract_kernel(const float* __restrict__ Dreg,
                                                       const int* __restrict__ comp2g,
                                                       unsigned long long* __restrict__ DcG,
                                                       int m0) {
  int q = blockIdx.x, mL = blockIdx.y, m = m0 + mL;
  const float* D = Dreg + (size_t)mL * NN2;
  __shared__ unsigned long long Dc[128 * 128];
  __shared__ int c2P[NN + 64];
  int tid = threadIdx.x;
  int wave = tid >> 6, lane = tid & 63;
  int c0 = lane * 8;
  if (tid < NN) c2P[tid + (tid >> 3)] = comp2g[(size_t)m * NN + tid];
  for (int i = tid; i < 16384; i += 512) Dc[i] = ~0ull;
  __syncthreads();
  #pragma unroll
  for (int rr = 0; rr < 16; ++rr) {
    int r = q * 128 + wave * 16 + rr;
    int di = c2P[r + (r >> 3)];
    const float4* rp = (const float4*)(D + (size_t)r * NN + c0);
    float4 v0 = rp[0], v1 = rp[1];
    int4 cc0 = *(const int4*)(c2P + c0 + (c0 >> 3));
    int4 cc1 = *(const int4*)(c2P + c0 + 4 + (c0 >> 3));
    float vv[8] = {v0.x, v0.y, v0.z, v0.w, v1.x, v1.y, v1.z, v1.w};
    int cv[8] = {cc0.x, cc0.y, cc0.z, cc0.w, cc1.x, cc1.y, cc1.z, cc1.w};
    #pragma unroll
    for (int e = 0; e < 8; ++e) {
      if (cv[e] != di) {
        int col = c0 + e;
        int lo = (r < col) ? r * NN + col : col * NN + r;
        unsigned long long key = ((unsigned long long)__float_as_uint(vv[e]) << 32) | (unsigned)lo;
        amin64(&Dc[di * 128 + cv[e]], key);
      }
    }
  }
  __syncthreads();
  unsigned long long* dg = DcG + (size_t)mL * 16384;
  for (int i = tid; i < 16384; i += 512) {
    unsigned long long v = Dc[i];
    if (v != ~0ull) atomicMin(&dg[i], v);
  }
}

// -------- finish: LDS-resident phases on contracted matrix + fused gather -------
__global__ __launch_bounds__(1024) void finish_kernel(const float* __restrict__ Dreg,
                                                      const unsigned long long* __restrict__ DcG,
                                                      const int* __restrict__ comp2g,
                                                      const int* __restrict__ cntG,
                                                      int2* __restrict__ eo_all,
                                                      int* __restrict__ ecntG,
                                                      const unsigned* __restrict__ maxBits,
                                                      float* __restrict__ out, int m0) {
  int mL = blockIdx.x, m = m0 + mL;
  __shared__ unsigned long long Dc[16384];
  __shared__ int c2n[NN];
  __shared__ unsigned long long best[128];
  __shared__ int comp2[128], hook128[128], parent128[128];
  __shared__ float fred[16];
  __shared__ int ecnt;
  int tid = threadIdx.x;
  int wave = tid >> 6, lane = tid & 63;
  const unsigned long long* dg = DcG + (size_t)mL * 16384;
  for (int i = tid; i < 16384; i += 1024) Dc[i] = dg[i];
  if (tid < NN) c2n[tid] = comp2g[(size_t)m * NN + tid];
  if (tid < 128) comp2[tid] = tid;
  if (tid == 0) ecnt = ecntG[m];
  __syncthreads();
  int C = cntG[m];
  int2* eo = eo_all + (size_t)m * (NN - 1);

  for (int ph = 0; ph < 7; ++ph) {
    if (ecnt >= NN - 1) break;
    if (tid < 128) best[tid] = ~0ull;
    __syncthreads();
    for (int i = tid; i < C * 128; i += 1024) {
      unsigned long long key = Dc[i];
      if (key == ~0ull) continue;
      int a = i >> 7, bb = i & 127;
      int ca = comp2[a], cb = comp2[bb];
      if (ca != cb) amin64(&best[ca], key);
    }
    __syncthreads();
    if (tid < C) {
      unsigned long long b = best[tid];
      int h;
      if (b != ~0ull) {
        int pid = (int)(unsigned)b;
        int er = pid >> 9, ec = pid & 511;
        int c1 = comp2[c2n[er]], c2v = comp2[c2n[ec]];
        h = (c1 == tid) ? c2v : c1;
      } else h = tid;
      hook128[tid] = h;
    }
    __syncthreads();
    if (tid < C) {
      unsigned long long b = best[tid];
      bool active = (b != ~0ull);
      int p = hook128[tid];
      bool mutual = active && (hook128[p] == tid);
      parent128[tid] = (!active) ? tid : ((mutual && tid < p) ? tid : p);
      if (active && (!mutual || tid > p)) {
        int pid = (int)(unsigned)b;
        int e = atomicAdd(&ecnt, 1);
        eo[e] = make_int2(pid >> 9, pid & 511);
      }
    }
    __syncthreads();
    if (tid < C) {
      int c = comp2[tid], pp = parent128[c];
      while (pp != c) { c = pp; pp = parent128[c]; }
      comp2[tid] = c;
    }
    __syncthreads();
  }
  __syncthreads();

  // fused loss gather
  int b = m >> 1;
  float mxX = fmaxf(__uint_as_float(maxBits[2 * b]), 1e-12f);
  float mxZ = fmaxf(__uint_as_float(maxBits[2 * b + 1]), 1e-12f);
  float rX = 1.0f / mxX, rZ = 1.0f / mxZ;
  const float* Dx = Dreg + (size_t)(mL & ~1) * NN2;
  const float* Dz = Dx + NN2;
  float acc = 0.f;
  if (tid < NN - 1) {
    int2 e = eo[tid];
    size_t off = (size_t)e.x * NN + e.y;
    float d = Dx[off] * rX - Dz[off] * rZ;
    acc = d * d;
  }
  #pragma unroll
  for (int o = 32; o > 0; o >>= 1) acc += __shfl_down(acc, o);
  if (lane == 0) fred[wave] = acc;
  __syncthreads();
  if (tid == 0) {
    float t = 0.f;
    #pragma unroll
    for (int i = 0; i < 16; ++i) t += fred[i];
    atomicAdd(out, t * (1.0f / NB));
  }
}

extern "C" void kernel_launch(void* const* d_in, const int* in_sizes, int n_in,
                              void* d_out, int out_size, void* d_ws, size_t ws_size,
                              hipStream_t stream) {
  const float* model = (const float*)d_in[0];
  const float* labels = (const float*)d_in[1];
  float* out = (float*)d_out;
  char* ws = (char*)d_ws;

  float*              sq      = (float*)(ws);                       // 131072
  unsigned*           maxBits = (unsigned*)(ws + 131072);           // -> 132096
  int2*               eo      = (int2*)(ws + 132096);               // -> 393728
  unsigned long long* best1   = (unsigned long long*)(ws + 393728); // -> 655872
  unsigned long long* best2   = (unsigned long long*)(ws + 655872); // -> 918016
  int*                compG   = (int*)(ws + 918016);                // -> 1049088
  int*                comp2g  = (int*)(ws + 1049088);               // -> 1180160
  int*                ecntG   = (int*)(ws + 1180160);               // -> 1180416
  int*                cntG    = (int*)(ws + 1180416);               // -> 1180672
  size_t base = 1181696;

  // per batch (2 matrices): D 2MB + Hi 1MB + Lo 1MB + Dc 256KB
  size_t perBatch = 2ull * (NN2 * sizeof(float) + 2ull * NN2 * 2 + 16384 * 8);
  size_t dcap = (ws_size > base) ? (ws_size - base) : 0;
  int cb = (int)(dcap / perBatch);
  if (cb > NB) cb = NB;
  if (cb < 1) cb = 1;
  int nmc = 2 * cb;

  float* Dreg = (float*)(ws + base);
  unsigned short* Hi = (unsigned short*)(ws + base + (size_t)nmc * NN2 * sizeof(float));
  unsigned short* Lo = Hi + (size_t)nmc * NN2;
  unsigned long long* DcG = (unsigned long long*)(Lo + (size_t)nmc * NN2);

  hipMemsetAsync(d_out, 0, sizeof(float), stream);
  hipMemsetAsync(maxBits, 0, 64 * sizeof(unsigned), stream);

  for (int b0 = 0; b0 < NB; b0 += cb) {
    int nb = (NB - b0 < cb) ? (NB - b0) : cb;
    int nm = 2 * nb, m0 = 2 * b0;
    hipMemsetAsync(best1 + (size_t)m0 * NN, 0xFF, (size_t)nm * NN * 8, stream);
    hipMemsetAsync(best2 + (size_t)m0 * NN, 0xFF, (size_t)nm * NN * 8, stream);
    hipMemsetAsync(DcG, 0xFF, (size_t)nm * 16384 * 8, stream);
    split_kernel<<<nm * 256, 256, 0, stream>>>(model, labels, Hi, Lo, sq, m0);
    gemm_dist<<<10 * nm, 256, 0, stream>>>(Hi, Lo, sq, Dreg, maxBits, best1, m0, nm);
    hook1_kernel<<<nm, 512, 0, stream>>>(best1, compG, eo, ecntG, m0);
    scan2_kernel<<<dim3(8, nm), 512, 0, stream>>>(Dreg, compG, best2, m0);
    hook2_kernel<<<nm, 512, 0, stream>>>(best2, compG, comp2g, eo, ecntG, cntG, m0);
    contract_kernel<<<dim3(4, nm), 512, 0, stream>>>(Dreg, comp2g, DcG, m0);
    finish_kernel<<<nm, 1024, 0, stream>>>(Dreg, DcG, comp2g, cntG, eo, ecntG,
                                           maxBits, out, m0);
  }
}

// Round 11
// 170.591 us; speedup vs baseline: 1.3061x; 1.3061x over previous
//
#include <hip/hip_runtime.h>
#include <math.h>

#define NN 512
#define NN2 (NN*NN)
#define NB 32
#define NM 64
#define LDH 40      // LDS row stride in bf16 units (80 B; 2-way banks on frag reads)

typedef __attribute__((ext_vector_type(8))) short short8v;   // 8 bf16 (4 VGPR)
typedef __attribute__((ext_vector_type(4))) float f32x4;     // MFMA acc

__device__ __forceinline__ float sigm(float x) { return 1.0f / (1.0f + expf(-x)); }

__device__ __forceinline__ unsigned short f2bf(float x) {
  unsigned u = __float_as_uint(x);
  return (unsigned short)((u + 0x7fffu + ((u >> 16) & 1u)) >> 16);   // RNE
}
__device__ __forceinline__ float bf2f(unsigned short h) {
  return __uint_as_float(((unsigned)h) << 16);
}
__device__ __forceinline__ unsigned long long u64min(unsigned long long a,
                                                     unsigned long long b) {
  return (b < a) ? b : a;
}
__device__ __forceinline__ void amin64(unsigned long long* p, unsigned long long v) {
  unsigned long long old = *p;
  while (v < old) {
    unsigned long long assumed = old;
    old = atomicCAS(p, assumed, v);
    if (old == assumed) break;
  }
}
template <int CTRL>
__device__ __forceinline__ unsigned long long dpp_min_u64(unsigned long long x) {
  int xlo = (int)(unsigned)x, xhi = (int)(unsigned)(x >> 32);
  int ylo = __builtin_amdgcn_update_dpp(xlo, xlo, CTRL, 0xf, 0xf, false);
  int yhi = __builtin_amdgcn_update_dpp(xhi, xhi, CTRL, 0xf, 0xf, false);
  unsigned long long y = ((unsigned long long)(unsigned)yhi << 32) | (unsigned)ylo;
  return (y < x) ? y : x;
}
__device__ __forceinline__ unsigned long long wave_min_u64(unsigned long long k) {
  k = dpp_min_u64<0x111>(k); k = dpp_min_u64<0x112>(k);
  k = dpp_min_u64<0x114>(k); k = dpp_min_u64<0x118>(k);
  k = dpp_min_u64<0x142>(k); k = dpp_min_u64<0x143>(k);
  return k;
}
__device__ __forceinline__ unsigned long long grp16_min_u64(unsigned long long k) {
  k = dpp_min_u64<0x111>(k); k = dpp_min_u64<0x112>(k);
  k = dpp_min_u64<0x114>(k); k = dpp_min_u64<0x118>(k);
  return k;
}

// -------- sigmoid + bf16 hi/lo split + fused row sums-of-squares ----------------
__global__ __launch_bounds__(256) void split_kernel(const float* __restrict__ model,
                                                    const float* __restrict__ labels,
                                                    unsigned short* __restrict__ Hi,
                                                    unsigned short* __restrict__ Lo,
                                                    float* __restrict__ sq, int m0) {
  int b = blockIdx.x;
  int mL = b >> 8;
  int m = m0 + mL;
  int tid = threadIdx.x;
  size_t off = (size_t)(b & 255) * 1024 + tid * 4;
  const float* src = ((m & 1) ? labels + (size_t)(m >> 1) * NN2
                              : model + (size_t)(m >> 1) * NN2) + off;
  float4 v = *(const float4*)src;
  if (!(m & 1)) { v.x = sigm(v.x); v.y = sigm(v.y); v.z = sigm(v.z); v.w = sigm(v.w); }
  ushort4 h, l;
  h.x = f2bf(v.x); l.x = f2bf(v.x - bf2f(h.x));
  h.y = f2bf(v.y); l.y = f2bf(v.y - bf2f(h.y));
  h.z = f2bf(v.z); l.z = f2bf(v.z - bf2f(h.z));
  h.w = f2bf(v.w); l.w = f2bf(v.w - bf2f(h.w));
  *(ushort4*)(Hi + (size_t)mL * NN2 + off) = h;
  *(ushort4*)(Lo + (size_t)mL * NN2 + off) = l;
  float s = v.x * v.x + v.y * v.y + v.z * v.z + v.w * v.w;
  #pragma unroll
  for (int o = 32; o > 0; o >>= 1) s += __shfl_down(s, o);
  __shared__ float red[4];
  if ((tid & 63) == 0) red[tid >> 6] = s;
  __syncthreads();
  if (tid == 0) {
    int row0 = (b & 255) * 2;
    sq[(size_t)m * NN + row0]     = red[0] + red[1];
    sq[(size_t)m * NN + row0 + 1] = red[2] + red[3];
  }
}

// ------- distance matrix: 3-pass split-bf16 MFMA, pipelined reg staging,
//         fully-coalesced D stores via per-wave LDS transpose -------------------
__global__ __launch_bounds__(256) void gemm_dist(const unsigned short* __restrict__ Hi,
                                                 const unsigned short* __restrict__ Lo,
                                                 const float* __restrict__ sq,
                                                 float* __restrict__ Dreg,
                                                 unsigned* __restrict__ maxBits,
                                                 unsigned long long* __restrict__ best1,
                                                 int m0, int nm) {
  __shared__ char smem[40960];      // staging (k-loop) then transpose scratch (epilogue)
  unsigned short* Ah = (unsigned short*)smem;
  unsigned short* Al = Ah + 128 * LDH;
  unsigned short* Bh = Al + 128 * LDH;
  unsigned short* Bl = Bh + 128 * LDH;
  // XCD-aware decode: blocks of one matrix land on one XCD (id%8 = XCD)
  int id = blockIdx.x;
  int p, mL;
  if ((nm & 7) == 0) {
    int x = id & 7, t = id >> 3;
    p = t % 10;
    mL = x + 8 * (t / 10);
  } else {
    p = id % 10;
    mL = id / 10;
  }
  int by = (p >= 4) + (p >= 7) + (p >= 9);
  int bx = p - ((by * (7 - by)) >> 1);
  bool diag = (by == bx);
  int m = m0 + mL;
  const unsigned short* Hm = Hi + (size_t)mL * NN2;
  const unsigned short* Lm = Lo + (size_t)mL * NN2;

  int tid = threadIdx.x;
  int wid = tid >> 6, lane = tid & 63;
  int wy = wid >> 1, wx = wid & 1;    // 2x2 waves of 64x64
  int lr = lane & 15, lk = lane >> 4;
  int trow = tid >> 1, tseg = tid & 1;  // staging: row 0..127, 16-bf16 segment

  f32x4 acc[4][4];
  #pragma unroll
  for (int i = 0; i < 4; ++i)
    #pragma unroll
    for (int j = 0; j < 4; ++j) acc[i][j] = (f32x4){0.f, 0.f, 0.f, 0.f};

  const unsigned short* gAh = Hm + (size_t)(by * 128 + trow) * NN + tseg * 16;
  const unsigned short* gAl = Lm + (size_t)(by * 128 + trow) * NN + tseg * 16;
  const unsigned short* gBh = Hm + (size_t)(bx * 128 + trow) * NN + tseg * 16;
  const unsigned short* gBl = Lm + (size_t)(bx * 128 + trow) * NN + tseg * 16;
  unsigned short* sAh = Ah + trow * LDH + tseg * 16;
  unsigned short* sAl = Al + trow * LDH + tseg * 16;
  unsigned short* sBh = Bh + trow * LDH + tseg * 16;
  unsigned short* sBl = Bl + trow * LDH + tseg * 16;

  const unsigned short* fAh = Ah + (wy * 64 + lr) * LDH + lk * 8;
  const unsigned short* fAl = Al + (wy * 64 + lr) * LDH + lk * 8;
  const unsigned short* fBh = (diag ? Ah : Bh) + (wx * 64 + lr) * LDH + lk * 8;
  const unsigned short* fBl = (diag ? Al : Bl) + (wx * 64 + lr) * LDH + lk * 8;

  // prologue loads (k0 = 0)
  uint4 ah0 = *(const uint4*)(gAh), ah1 = *(const uint4*)(gAh + 8);
  uint4 al0 = *(const uint4*)(gAl), al1 = *(const uint4*)(gAl + 8);
  uint4 bh0, bh1, bl0, bl1;
  if (!diag) {
    bh0 = *(const uint4*)(gBh); bh1 = *(const uint4*)(gBh + 8);
    bl0 = *(const uint4*)(gBl); bl1 = *(const uint4*)(gBl + 8);
  }

  for (int s = 0; s < 16; ++s) {
    __syncthreads();                 // prev step's frag reads complete
    *(uint4*)(sAh) = ah0; *(uint4*)(sAh + 8) = ah1;
    *(uint4*)(sAl) = al0; *(uint4*)(sAl + 8) = al1;
    if (!diag) {
      *(uint4*)(sBh) = bh0; *(uint4*)(sBh + 8) = bh1;
      *(uint4*)(sBl) = bl0; *(uint4*)(sBl + 8) = bl1;
    }
    __syncthreads();
    // issue next step's loads: latency hides under frag reads + 48 MFMAs
    if (s < 15) {
      int k0 = (s + 1) * 32;
      ah0 = *(const uint4*)(gAh + k0); ah1 = *(const uint4*)(gAh + k0 + 8);
      al0 = *(const uint4*)(gAl + k0); al1 = *(const uint4*)(gAl + k0 + 8);
      if (!diag) {
        bh0 = *(const uint4*)(gBh + k0); bh1 = *(const uint4*)(gBh + k0 + 8);
        bl0 = *(const uint4*)(gBl + k0); bl1 = *(const uint4*)(gBl + k0 + 8);
      }
    }

    short8v avh[4], avl[4], bvh[4], bvl[4];
    #pragma unroll
    for (int i = 0; i < 4; ++i) {
      avh[i] = *(const short8v*)(fAh + i * 16 * LDH);
      avl[i] = *(const short8v*)(fAl + i * 16 * LDH);
      bvh[i] = *(const short8v*)(fBh + i * 16 * LDH);
      bvl[i] = *(const short8v*)(fBl + i * 16 * LDH);
    }
    #pragma unroll
    for (int mi = 0; mi < 4; ++mi)
      #pragma unroll
      for (int ni = 0; ni < 4; ++ni)
        acc[mi][ni] = __builtin_amdgcn_mfma_f32_16x16x32_bf16(avh[mi], bvh[ni], acc[mi][ni], 0, 0, 0);
    #pragma unroll
    for (int mi = 0; mi < 4; ++mi)
      #pragma unroll
      for (int ni = 0; ni < 4; ++ni)
        acc[mi][ni] = __builtin_amdgcn_mfma_f32_16x16x32_bf16(avh[mi], bvl[ni], acc[mi][ni], 0, 0, 0);
    #pragma unroll
    for (int mi = 0; mi < 4; ++mi)
      #pragma unroll
      for (int ni = 0; ni < 4; ++ni)
        acc[mi][ni] = __builtin_amdgcn_mfma_f32_16x16x32_bf16(avl[mi], bvh[ni], acc[mi][ni], 0, 0, 0);
  }

  const float* sqm = sq + (size_t)m * NN;
  float* Dm = Dreg + (size_t)mL * NN2;
  int gr0 = by * 128 + wy * 64;
  int gc0 = bx * 128 + wx * 64;
  float tmax = 0.f;
  unsigned long long rk[4][4];
  unsigned long long ck[4];
  #pragma unroll
  for (int i = 0; i < 4; ++i) {
    ck[i] = ~0ull;
    #pragma unroll
    for (int j = 0; j < 4; ++j) rk[i][j] = ~0ull;
  }
  // convert acc -> distances in place; fused max + phase-1 argmin keys
  #pragma unroll
  for (int mi = 0; mi < 4; ++mi) {
    int rb = gr0 + mi * 16 + lk * 4;
    float sqi0 = sqm[rb + 0], sqi1 = sqm[rb + 1], sqi2 = sqm[rb + 2], sqi3 = sqm[rb + 3];
    #pragma unroll
    for (int ni = 0; ni < 4; ++ni) {
      int col = gc0 + ni * 16 + lr;
      float sqj = sqm[col];
      f32x4 a = acc[mi][ni];
      float v0 = sqrtf(fmaxf(sqi0 + sqj - 2.f * a[0], 0.f));
      float v1 = sqrtf(fmaxf(sqi1 + sqj - 2.f * a[1], 0.f));
      float v2 = sqrtf(fmaxf(sqi2 + sqj - 2.f * a[2], 0.f));
      float v3 = sqrtf(fmaxf(sqi3 + sqj - 2.f * a[3], 0.f));
      acc[mi][ni][0] = v0; acc[mi][ni][1] = v1;
      acc[mi][ni][2] = v2; acc[mi][ni][3] = v3;
      tmax = fmaxf(tmax, fmaxf(fmaxf(v0, v1), fmaxf(v2, v3)));
      float vv[4] = {v0, v1, v2, v3};
      #pragma unroll
      for (int rg = 0; rg < 4; ++rg) {
        int row = rb + rg;
        if (!diag || col != row) {
          unsigned lo = (row < col) ? (unsigned)(row * NN + col)
                                    : (unsigned)(col * NN + row);
          unsigned long long key =
              ((unsigned long long)__float_as_uint(vv[rg]) << 32) | lo;
          rk[mi][rg] = u64min(rk[mi][rg], key);
          ck[ni] = u64min(ck[ni], key);
        }
      }
    }
  }

  // ---- coalesced D stores via per-wave LDS transpose (values identical) ----
  __syncthreads();                  // staging LDS dead for ALL waves now
  float* W = (float*)smem + wid * 1088;     // 16 x 68 f32 per-wave scratch
  int rlo = lane >> 4, cq = lane & 15;      // read/store lane mapping
  // direct part: rows gr0+mi*16+0..15, cols gc0+0..63
  #pragma unroll
  for (int mi = 0; mi < 4; ++mi) {
    #pragma unroll
    for (int ni = 0; ni < 4; ++ni)
      #pragma unroll
      for (int j = 0; j < 4; ++j)
        W[(lk * 4 + j) * 68 + ni * 16 + lr] = acc[mi][ni][j];
    #pragma unroll
    for (int g = 0; g < 4; ++g) {
      int r16 = g * 4 + rlo;
      float4 t = *(const float4*)&W[r16 * 68 + cq * 4];
      *(float4*)(Dm + (size_t)(gr0 + mi * 16 + r16) * NN + gc0 + cq * 4) = t;
    }
  }
  // mirror part: rows gc0+ni*16+0..15, cols gr0+0..63 (non-diag only)
  if (!diag) {
    #pragma unroll
    for (int ni = 0; ni < 4; ++ni) {
      #pragma unroll
      for (int mi = 0; mi < 4; ++mi) {
        f32x4 a = acc[mi][ni];
        *(float4*)&W[lr * 68 + mi * 16 + lk * 4] = make_float4(a[0], a[1], a[2], a[3]);
      }
      #pragma unroll
      for (int g = 0; g < 4; ++g) {
        int r16 = g * 4 + rlo;
        float4 t = *(const float4*)&W[r16 * 68 + cq * 4];
        *(float4*)(Dm + (size_t)(gc0 + ni * 16 + r16) * NN + gr0 + cq * 4) = t;
      }
    }
  }

  unsigned long long* b1 = best1 + (size_t)m * NN;
  #pragma unroll
  for (int mi = 0; mi < 4; ++mi)
    #pragma unroll
    for (int rg = 0; rg < 4; ++rg) {
      unsigned long long k = grp16_min_u64(rk[mi][rg]);
      if (lr == 15) atomicMin(&b1[gr0 + mi * 16 + lk * 4 + rg], k);
    }
  if (!diag) {
    #pragma unroll
    for (int ni = 0; ni < 4; ++ni) {
      unsigned long long k = ck[ni];
      k = u64min(k, __shfl_xor(k, 16));
      k = u64min(k, __shfl_xor(k, 32));
      if (lk == 0) atomicMin(&b1[gc0 + ni * 16 + lr], k);
    }
  }
  #pragma unroll
  for (int off = 32; off > 0; off >>= 1) tmax = fmaxf(tmax, __shfl_down(tmax, off));
  if (lane == 0) atomicMax(&maxBits[m], __float_as_uint(tmax));
}

// -------- phase-1 hook (comp = identity), emit edges, write comp labels ---------
__global__ __launch_bounds__(512) void hook1_kernel(const unsigned long long* __restrict__ best1,
                                                    int* __restrict__ compG,
                                                    int2* __restrict__ eo_all,
                                                    int* __restrict__ ecntG, int m0) {
  int mL = blockIdx.x, m = m0 + mL;
  const unsigned long long* b1 = best1 + (size_t)m * NN;
  int2* eo = eo_all + (size_t)m * (NN - 1);
  __shared__ int hook[NN], parent[NN];
  __shared__ int ecnt;
  int tid = threadIdx.x;
  if (tid == 0) ecnt = 0;
  unsigned long long b = b1[tid];
  int h;
  if (b != ~0ull) {
    int idx = (int)(unsigned)b;
    int er = idx >> 9, ec = idx & 511;
    h = (er == tid) ? ec : er;
  } else h = tid;
  hook[tid] = h;
  __syncthreads();
  bool active = (b != ~0ull);
  int p = h;
  bool mutual = active && (hook[p] == tid);
  parent[tid] = (!active) ? tid : ((mutual && tid < p) ? tid : p);
  if (active && (!mutual || tid > p)) {
    int idx = (int)(unsigned)b;
    int e = atomicAdd(&ecnt, 1);
    eo[e] = make_int2(idx >> 9, idx & 511);
  }
  __syncthreads();
  int c = tid, pp = parent[c];
  while (pp != c) { c = pp; pp = parent[c]; }
  compG[(size_t)m * NN + tid] = c;
  if (tid == 0) ecntG[m] = ecnt;
}

// -------- phase-2 scan: 8 blocks/matrix, wave-per-row, atomicMin per comp -------
__global__ __launch_bounds__(512) void scan2_kernel(const float* __restrict__ Dreg,
                                                    const int* __restrict__ compG,
                                                    unsigned long long* __restrict__ best2,
                                                    int m0) {
  int sblk = blockIdx.x, mL = blockIdx.y, m = m0 + mL;
  const float* D = Dreg + (size_t)mL * NN2;
  __shared__ int compP[NN + 64];
  int tid = threadIdx.x;
  int wave = tid >> 6, lane = tid & 63;
  int c0 = lane * 8;
  if (tid < NN) compP[tid + (tid >> 3)] = compG[(size_t)m * NN + tid];
  __syncthreads();
  unsigned long long* b2 = best2 + (size_t)m * NN;
  #pragma unroll
  for (int rr = 0; rr < 8; ++rr) {
    int r = sblk * 64 + wave * 8 + rr;
    int cr = compP[r + (r >> 3)];
    const float4* rp = (const float4*)(D + (size_t)r * NN + c0);
    float4 v0 = rp[0], v1 = rp[1];
    int4 cc0 = *(const int4*)(compP + c0 + (c0 >> 3));
    int4 cc1 = *(const int4*)(compP + c0 + 4 + (c0 >> 3));
    float vv[8] = {v0.x, v0.y, v0.z, v0.w, v1.x, v1.y, v1.z, v1.w};
    int cv[8] = {cc0.x, cc0.y, cc0.z, cc0.w, cc1.x, cc1.y, cc1.z, cc1.w};
    unsigned long long k = ~0ull;
    #pragma unroll
    for (int e = 0; e < 8; ++e) {
      if (cv[e] != cr) {
        int col = c0 + e;
        int lo = (r < col) ? r * NN + col : col * NN + r;
        unsigned long long key = ((unsigned long long)__float_as_uint(vv[e]) << 32) | (unsigned)lo;
        k = u64min(k, key);
      }
    }
    k = wave_min_u64(k);
    if (lane == 63 && k != ~0ull) atomicMin(&b2[cr], k);
  }
}

// -------- phase-2 hook + dense remap (C <= 128 guaranteed) ----------------------
__global__ __launch_bounds__(512) void hook2_kernel(const unsigned long long* __restrict__ best2,
                                                    const int* __restrict__ compG,
                                                    int* __restrict__ comp2g,
                                                    int2* __restrict__ eo_all,
                                                    int* __restrict__ ecntG,
                                                    int* __restrict__ cntG, int m0) {
  int mL = blockIdx.x, m = m0 + mL;
  const unsigned long long* b2 = best2 + (size_t)m * NN;
  int2* eo = eo_all + (size_t)m * (NN - 1);
  __shared__ int comp[NN], hook[NN], parent[NN], dmap[NN];
  __shared__ int ecnt, ccnt;
  int tid = threadIdx.x;
  if (tid == 0) { ecnt = ecntG[m]; ccnt = 0; }
  comp[tid] = compG[(size_t)m * NN + tid];
  __syncthreads();
  unsigned long long b = b2[tid];
  int h;
  if (b != ~0ull) {
    int idx = (int)(unsigned)b;
    int er = idx >> 9, ec = idx & 511;
    int c1 = comp[er], c2 = comp[ec];
    h = (c1 == tid) ? c2 : c1;
  } else h = tid;
  hook[tid] = h;
  __syncthreads();
  bool active = (b != ~0ull);
  int p = h;
  bool mutual = active && (hook[p] == tid);
  parent[tid] = (!active) ? tid : ((mutual && tid < p) ? tid : p);
  if (active && (!mutual || tid > p)) {
    int idx = (int)(unsigned)b;
    int e = atomicAdd(&ecnt, 1);
    eo[e] = make_int2(idx >> 9, idx & 511);
  }
  __syncthreads();
  int c = comp[tid], pp = parent[c];
  while (pp != c) { c = pp; pp = parent[c]; }
  __syncthreads();
  comp[tid] = c;
  __syncthreads();
  if (comp[tid] == tid) dmap[tid] = atomicAdd(&ccnt, 1);
  __syncthreads();
  comp2g[(size_t)m * NN + tid] = dmap[comp[tid]];
  if (tid == 0) { ecntG[m] = ecnt; cntG[m] = ccnt; }
}

// -------- contraction: 4 blocks/matrix build LDS-partial Dc, merge to global ----
__global__ __launch_bounds__(512) void contract_kernel(const float* __restrict__ Dreg,
                                                       const int* __restrict__ comp2g,
                                                       unsigned long long* __restrict__ DcG,
                                                       int m0) {
  int q = blockIdx.x, mL = blockIdx.y, m = m0 + mL;
  const float* D = Dreg + (size_t)mL * NN2;
  __shared__ unsigned long long Dc[128 * 128];
  __shared__ int c2P[NN + 64];
  int tid = threadIdx.x;
  int wave = tid >> 6, lane = tid & 63;
  int c0 = lane * 8;
  if (tid < NN) c2P[tid + (tid >> 3)] = comp2g[(size_t)m * NN + tid];
  for (int i = tid; i < 16384; i += 512) Dc[i] = ~0ull;
  __syncthreads();
  #pragma unroll
  for (int rr = 0; rr < 16; ++rr) {
    int r = q * 128 + wave * 16 + rr;
    int di = c2P[r + (r >> 3)];
    const float4* rp = (const float4*)(D + (size_t)r * NN + c0);
    float4 v0 = rp[0], v1 = rp[1];
    int4 cc0 = *(const int4*)(c2P + c0 + (c0 >> 3));
    int4 cc1 = *(const int4*)(c2P + c0 + 4 + (c0 >> 3));
    float vv[8] = {v0.x, v0.y, v0.z, v0.w, v1.x, v1.y, v1.z, v1.w};
    int cv[8] = {cc0.x, cc0.y, cc0.z, cc0.w, cc1.x, cc1.y, cc1.z, cc1.w};
    #pragma unroll
    for (int e = 0; e < 8; ++e) {
      if (cv[e] != di) {
        int col = c0 + e;
        int lo = (r < col) ? r * NN + col : col * NN + r;
        unsigned long long key = ((unsigned long long)__float_as_uint(vv[e]) << 32) | (unsigned)lo;
        amin64(&Dc[di * 128 + cv[e]], key);
      }
    }
  }
  __syncthreads();
  unsigned long long* dg = DcG + (size_t)mL * 16384;
  for (int i = tid; i < 16384; i += 512) {
    unsigned long long v = Dc[i];
    if (v != ~0ull) atomicMin(&dg[i], v);
  }
}

// -------- finish: LDS-resident phases on contracted matrix + fused gather -------
__global__ __launch_bounds__(1024) void finish_kernel(const float* __restrict__ Dreg,
                                                      const unsigned long long* __restrict__ DcG,
                                                      const int* __restrict__ comp2g,
                                                      const int* __restrict__ cntG,
                                                      int2* __restrict__ eo_all,
                                                      int* __restrict__ ecntG,
                                                      const unsigned* __restrict__ maxBits,
                                                      float* __restrict__ out, int m0) {
  int mL = blockIdx.x, m = m0 + mL;
  __shared__ unsigned long long Dc[16384];
  __shared__ int c2n[NN];
  __shared__ unsigned long long best[128];
  __shared__ int comp2[128], hook128[128], parent128[128];
  __shared__ float fred[16];
  __shared__ int ecnt;
  int tid = threadIdx.x;
  int wave = tid >> 6, lane = tid & 63;
  const unsigned long long* dg = DcG + (size_t)mL * 16384;
  for (int i = tid; i < 16384; i += 1024) Dc[i] = dg[i];
  if (tid < NN) c2n[tid] = comp2g[(size_t)m * NN + tid];
  if (tid < 128) comp2[tid] = tid;
  if (tid == 0) ecnt = ecntG[m];
  __syncthreads();
  int C = cntG[m];
  int2* eo = eo_all + (size_t)m * (NN - 1);

  for (int ph = 0; ph < 7; ++ph) {
    if (ecnt >= NN - 1) break;
    if (tid < 128) best[tid] = ~0ull;
    __syncthreads();
    for (int i = tid; i < C * 128; i += 1024) {
      unsigned long long key = Dc[i];
      if (key == ~0ull) continue;
      int a = i >> 7, bb = i & 127;
      int ca = comp2[a], cb = comp2[bb];
      if (ca != cb) amin64(&best[ca], key);
    }
    __syncthreads();
    if (tid < C) {
      unsigned long long b = best[tid];
      int h;
      if (b != ~0ull) {
        int pid = (int)(unsigned)b;
        int er = pid >> 9, ec = pid & 511;
        int c1 = comp2[c2n[er]], c2v = comp2[c2n[ec]];
        h = (c1 == tid) ? c2v : c1;
      } else h = tid;
      hook128[tid] = h;
    }
    __syncthreads();
    if (tid < C) {
      unsigned long long b = best[tid];
      bool active = (b != ~0ull);
      int p = hook128[tid];
      bool mutual = active && (hook128[p] == tid);
      parent128[tid] = (!active) ? tid : ((mutual && tid < p) ? tid : p);
      if (active && (!mutual || tid > p)) {
        int pid = (int)(unsigned)b;
        int e = atomicAdd(&ecnt, 1);
        eo[e] = make_int2(pid >> 9, pid & 511);
      }
    }
    __syncthreads();
    if (tid < C) {
      int c = comp2[tid], pp = parent128[c];
      while (pp != c) { c = pp; pp = parent128[c]; }
      comp2[tid] = c;
    }
    __syncthreads();
  }
  __syncthreads();

  // fused loss gather
  int b = m >> 1;
  float mxX = fmaxf(__uint_as_float(maxBits[2 * b]), 1e-12f);
  float mxZ = fmaxf(__uint_as_float(maxBits[2 * b + 1]), 1e-12f);
  float rX = 1.0f / mxX, rZ = 1.0f / mxZ;
  const float* Dx = Dreg + (size_t)(mL & ~1) * NN2;
  const float* Dz = Dx + NN2;
  float acc = 0.f;
  if (tid < NN - 1) {
    int2 e = eo[tid];
    size_t off = (size_t)e.x * NN + e.y;
    float d = Dx[off] * rX - Dz[off] * rZ;
    acc = d * d;
  }
  #pragma unroll
  for (int o = 32; o > 0; o >>= 1) acc += __shfl_down(acc, o);
  if (lane == 0) fred[wave] = acc;
  __syncthreads();
  if (tid == 0) {
    float t = 0.f;
    #pragma unroll
    for (int i = 0; i < 16; ++i) t += fred[i];
    atomicAdd(out, t * (1.0f / NB));
  }
}

extern "C" void kernel_launch(void* const* d_in, const int* in_sizes, int n_in,
                              void* d_out, int out_size, void* d_ws, size_t ws_size,
                              hipStream_t stream) {
  const float* model = (const float*)d_in[0];
  const float* labels = (const float*)d_in[1];
  float* out = (float*)d_out;
  char* ws = (char*)d_ws;

  float*              sq      = (float*)(ws);                       // 131072
  unsigned*           maxBits = (unsigned*)(ws + 131072);           // -> 132096
  int2*               eo      = (int2*)(ws + 132096);               // -> 393728
  unsigned long long* best1   = (unsigned long long*)(ws + 393728); // -> 655872
  unsigned long long* best2   = (unsigned long long*)(ws + 655872); // -> 918016
  int*                compG   = (int*)(ws + 918016);                // -> 1049088
  int*                comp2g  = (int*)(ws + 1049088);               // -> 1180160
  int*                ecntG   = (int*)(ws + 1180160);               // -> 1180416
  int*                cntG    = (int*)(ws + 1180416);               // -> 1180672
  size_t base = 1181696;

  // per batch (2 matrices): D 2MB + Hi 1MB + Lo 1MB + Dc 256KB
  size_t perBatch = 2ull * (NN2 * sizeof(float) + 2ull * NN2 * 2 + 16384 * 8);
  size_t dcap = (ws_size > base) ? (ws_size - base) : 0;
  int cb = (int)(dcap / perBatch);
  if (cb > NB) cb = NB;
  if (cb < 1) cb = 1;
  int nmc = 2 * cb;

  float* Dreg = (float*)(ws + base);
  unsigned short* Hi = (unsigned short*)(ws + base + (size_t)nmc * NN2 * sizeof(float));
  unsigned short* Lo = Hi + (size_t)nmc * NN2;
  unsigned long long* DcG = (unsigned long long*)(Lo + (size_t)nmc * NN2);

  hipMemsetAsync(d_out, 0, sizeof(float), stream);
  hipMemsetAsync(maxBits, 0, 64 * sizeof(unsigned), stream);

  for (int b0 = 0; b0 < NB; b0 += cb) {
    int nb = (NB - b0 < cb) ? (NB - b0) : cb;
    int nm = 2 * nb, m0 = 2 * b0;
    hipMemsetAsync(best1 + (size_t)m0 * NN, 0xFF, (size_t)nm * NN * 8, stream);
    hipMemsetAsync(best2 + (size_t)m0 * NN, 0xFF, (size_t)nm * NN * 8, stream);
    hipMemsetAsync(DcG, 0xFF, (size_t)nm * 16384 * 8, stream);
    split_kernel<<<nm * 256, 256, 0, stream>>>(model, labels, Hi, Lo, sq, m0);
    gemm_dist<<<10 * nm, 256, 0, stream>>>(Hi, Lo, sq, Dreg, maxBits, best1, m0, nm);
    hook1_kernel<<<nm, 512, 0, stream>>>(best1, compG, eo, ecntG, m0);
    scan2_kernel<<<dim3(8, nm), 512, 0, stream>>>(Dreg, compG, best2, m0);
    hook2_kernel<<<nm, 512, 0, stream>>>(best2, compG, comp2g, eo, ecntG, cntG, m0);
    contract_kernel<<<dim3(4, nm), 512, 0, stream>>>(Dreg, comp2g, DcG, m0);
    finish_kernel<<<nm, 1024, 0, stream>>>(Dreg, DcG, comp2g, cntG, eo, ecntG,
                                           maxBits, out, m0);
  }
}

// Round 12
// 163.376 us; speedup vs baseline: 1.3638x; 1.0442x over previous
//
#include <hip/hip_runtime.h>
#include <math.h>

#define NN 512
#define NN2 (NN*NN)
#define NB 32
#define NM 64

typedef __attribute__((ext_vector_type(8))) short short8v;   // 8 bf16 (4 VGPR)
typedef __attribute__((ext_vector_type(4))) float f32x4;     // MFMA acc

typedef const unsigned int __attribute__((address_space(1)))* gas_ptr;
typedef unsigned int __attribute__((address_space(3)))* las_ptr;

__device__ __forceinline__ float sigm(float x) { return 1.0f / (1.0f + expf(-x)); }

__device__ __forceinline__ unsigned short f2bf(float x) {
  unsigned u = __float_as_uint(x);
  return (unsigned short)((u + 0x7fffu + ((u >> 16) & 1u)) >> 16);   // RNE
}
__device__ __forceinline__ float bf2f(unsigned short h) {
  return __uint_as_float(((unsigned)h) << 16);
}
__device__ __forceinline__ unsigned long long u64min(unsigned long long a,
                                                     unsigned long long b) {
  return (b < a) ? b : a;
}
__device__ __forceinline__ void amin64(unsigned long long* p, unsigned long long v) {
  unsigned long long old = *p;
  while (v < old) {
    unsigned long long assumed = old;
    old = atomicCAS(p, assumed, v);
    if (old == assumed) break;
  }
}
template <int CTRL>
__device__ __forceinline__ unsigned long long dpp_min_u64(unsigned long long x) {
  int xlo = (int)(unsigned)x, xhi = (int)(unsigned)(x >> 32);
  int ylo = __builtin_amdgcn_update_dpp(xlo, xlo, CTRL, 0xf, 0xf, false);
  int yhi = __builtin_amdgcn_update_dpp(xhi, xhi, CTRL, 0xf, 0xf, false);
  unsigned long long y = ((unsigned long long)(unsigned)yhi << 32) | (unsigned)ylo;
  return (y < x) ? y : x;
}
__device__ __forceinline__ unsigned long long wave_min_u64(unsigned long long k) {
  k = dpp_min_u64<0x111>(k); k = dpp_min_u64<0x112>(k);
  k = dpp_min_u64<0x114>(k); k = dpp_min_u64<0x118>(k);
  k = dpp_min_u64<0x142>(k); k = dpp_min_u64<0x143>(k);
  return k;
}
__device__ __forceinline__ unsigned long long grp16_min_u64(unsigned long long k) {
  k = dpp_min_u64<0x111>(k); k = dpp_min_u64<0x112>(k);
  k = dpp_min_u64<0x114>(k); k = dpp_min_u64<0x118>(k);
  return k;
}

// -------- sigmoid + bf16 hi/lo split + fused row sums-of-squares ----------------
__global__ __launch_bounds__(256) void split_kernel(const float* __restrict__ model,
                                                    const float* __restrict__ labels,
                                                    unsigned short* __restrict__ Hi,
                                                    unsigned short* __restrict__ Lo,
                                                    float* __restrict__ sq, int m0) {
  int b = blockIdx.x;
  int mL = b >> 8;
  int m = m0 + mL;
  int tid = threadIdx.x;
  size_t off = (size_t)(b & 255) * 1024 + tid * 4;
  const float* src = ((m & 1) ? labels + (size_t)(m >> 1) * NN2
                              : model + (size_t)(m >> 1) * NN2) + off;
  float4 v = *(const float4*)src;
  if (!(m & 1)) { v.x = sigm(v.x); v.y = sigm(v.y); v.z = sigm(v.z); v.w = sigm(v.w); }
  ushort4 h, l;
  h.x = f2bf(v.x); l.x = f2bf(v.x - bf2f(h.x));
  h.y = f2bf(v.y); l.y = f2bf(v.y - bf2f(h.y));
  h.z = f2bf(v.z); l.z = f2bf(v.z - bf2f(h.z));
  h.w = f2bf(v.w); l.w = f2bf(v.w - bf2f(h.w));
  *(ushort4*)(Hi + (size_t)mL * NN2 + off) = h;
  *(ushort4*)(Lo + (size_t)mL * NN2 + off) = l;
  float s = v.x * v.x + v.y * v.y + v.z * v.z + v.w * v.w;
  #pragma unroll
  for (int o = 32; o > 0; o >>= 1) s += __shfl_down(s, o);
  __shared__ float red[4];
  if ((tid & 63) == 0) red[tid >> 6] = s;
  __syncthreads();
  if (tid == 0) {
    int row0 = (b & 255) * 2;
    sq[(size_t)m * NN + row0]     = red[0] + red[1];
    sq[(size_t)m * NN + row0 + 1] = red[2] + red[3];
  }
}

// ------- distance matrix: 3-pass split-bf16 MFMA with global_load_lds staging ---
// LDS panels linear [128][32] bf16; XOR chunk-swizzle (chunk' = chunk ^ ((row>>1)&3))
// applied on the pre-swizzled GLOBAL source (m173 pattern): gload_lds dest stays
// linear (conflict-free DMA writes), frag reads land 2-way (free) on banks.
__global__ __launch_bounds__(256) void gemm_dist(const unsigned short* __restrict__ Hi,
                                                 const unsigned short* __restrict__ Lo,
                                                 const float* __restrict__ sq,
                                                 float* __restrict__ Dreg,
                                                 unsigned* __restrict__ maxBits,
                                                 unsigned long long* __restrict__ best1,
                                                 int m0, int nm) {
  __shared__ unsigned short P[4][128 * 32];   // Ah, Al, Bh, Bl (8 KB each)
  // XCD-aware decode: blocks of one matrix land on one XCD (id%8 = XCD)
  int id = blockIdx.x;
  int p, mL;
  if ((nm & 7) == 0) {
    int x = id & 7, t = id >> 3;
    p = t % 10;
    mL = x + 8 * (t / 10);
  } else {
    p = id % 10;
    mL = id / 10;
  }
  int by = (p >= 4) + (p >= 7) + (p >= 9);
  int bx = p - ((by * (7 - by)) >> 1);
  bool diag = (by == bx);
  int m = m0 + mL;
  const unsigned short* Hm = Hi + (size_t)mL * NN2;
  const unsigned short* Lm = Lo + (size_t)mL * NN2;

  int tid = threadIdx.x;
  int wid = tid >> 6, lane = tid & 63;
  int wy = wid >> 1, wx = wid & 1;    // 2x2 waves of 64x64
  int lr = lane & 15, lk = lane >> 4;

  // staging: wave wid owns panel wid (Ah,Al,Bh,Bl); diag blocks skip B panels
  const unsigned short* wsrcM = (wid & 1) ? Lm : Hm;
  int wrow0 = (wid < 2) ? by * 128 : bx * 128;
  bool stage = (!diag) || (wid < 2);
  // per-lane source: row group-offset lane>>2, swizzled 16B chunk
  int srow = lane >> 2;
  int schunk = (lane & 3) ^ ((lane >> 3) & 3);
  const unsigned short* gsrc = wsrcM + (size_t)(wrow0 + srow) * NN + schunk * 8;
  unsigned short* ldst = &P[wid & 3][0];

  f32x4 acc[4][4];
  #pragma unroll
  for (int i = 0; i < 4; ++i)
    #pragma unroll
    for (int j = 0; j < 4; ++j) acc[i][j] = (f32x4){0.f, 0.f, 0.f, 0.f};

  const unsigned short* bAh = &P[0][0];
  const unsigned short* bAl = &P[1][0];
  const unsigned short* bBh = diag ? &P[0][0] : &P[2][0];
  const unsigned short* bBl = diag ? &P[1][0] : &P[3][0];
  int sw = (lr >> 1) & 3;                       // read-side swizzle (lane-only)
  int rao = (wy * 64 + lr) * 32 + (lk ^ sw) * 8;  // A frag base index (panel shorts)
  int rbo = (wx * 64 + lr) * 32 + (lk ^ sw) * 8;  // B frag base index

  for (int s = 0; s < 16; ++s) {
    int k0 = s * 32;
    if (stage) {
      #pragma unroll
      for (int i = 0; i < 8; ++i)
        __builtin_amdgcn_global_load_lds(
            (gas_ptr)(const void*)(gsrc + k0 + (size_t)i * 16 * NN),
            (las_ptr)(void*)(ldst + i * 512), 16, 0, 0);
    }
    __syncthreads();                 // drains vmcnt: panels landed

    short8v avh[4], avl[4], bvh[4], bvl[4];
    #pragma unroll
    for (int i = 0; i < 4; ++i) {
      avh[i] = *(const short8v*)(bAh + rao + i * 16 * 32);
      avl[i] = *(const short8v*)(bAl + rao + i * 16 * 32);
      bvh[i] = *(const short8v*)(bBh + rbo + i * 16 * 32);
      bvl[i] = *(const short8v*)(bBl + rbo + i * 16 * 32);
    }
    #pragma unroll
    for (int mi = 0; mi < 4; ++mi)
      #pragma unroll
      for (int ni = 0; ni < 4; ++ni)
        acc[mi][ni] = __builtin_amdgcn_mfma_f32_16x16x32_bf16(avh[mi], bvh[ni], acc[mi][ni], 0, 0, 0);
    #pragma unroll
    for (int mi = 0; mi < 4; ++mi)
      #pragma unroll
      for (int ni = 0; ni < 4; ++ni)
        acc[mi][ni] = __builtin_amdgcn_mfma_f32_16x16x32_bf16(avh[mi], bvl[ni], acc[mi][ni], 0, 0, 0);
    #pragma unroll
    for (int mi = 0; mi < 4; ++mi)
      #pragma unroll
      for (int ni = 0; ni < 4; ++ni)
        acc[mi][ni] = __builtin_amdgcn_mfma_f32_16x16x32_bf16(avl[mi], bvh[ni], acc[mi][ni], 0, 0, 0);
    __syncthreads();                 // all frag reads done before next overwrite
  }

  const float* sqm = sq + (size_t)m * NN;
  float* Dm = Dreg + (size_t)mL * NN2;
  int gr0 = by * 128 + wy * 64;
  int gc0 = bx * 128 + wx * 64;
  float tmax = 0.f;
  unsigned long long rk[4][4];
  unsigned long long ck[4];
  #pragma unroll
  for (int i = 0; i < 4; ++i) {
    ck[i] = ~0ull;
    #pragma unroll
    for (int j = 0; j < 4; ++j) rk[i][j] = ~0ull;
  }
  #pragma unroll
  for (int mi = 0; mi < 4; ++mi) {
    int rb = gr0 + mi * 16 + lk * 4;
    float sqi0 = sqm[rb + 0], sqi1 = sqm[rb + 1], sqi2 = sqm[rb + 2], sqi3 = sqm[rb + 3];
    #pragma unroll
    for (int ni = 0; ni < 4; ++ni) {
      int col = gc0 + ni * 16 + lr;
      float sqj = sqm[col];
      f32x4 a = acc[mi][ni];
      float v0 = sqrtf(fmaxf(sqi0 + sqj - 2.f * a[0], 0.f));
      float v1 = sqrtf(fmaxf(sqi1 + sqj - 2.f * a[1], 0.f));
      float v2 = sqrtf(fmaxf(sqi2 + sqj - 2.f * a[2], 0.f));
      float v3 = sqrtf(fmaxf(sqi3 + sqj - 2.f * a[3], 0.f));
      Dm[(size_t)(rb + 0) * NN + col] = v0;
      Dm[(size_t)(rb + 1) * NN + col] = v1;
      Dm[(size_t)(rb + 2) * NN + col] = v2;
      Dm[(size_t)(rb + 3) * NN + col] = v3;
      if (!diag)
        *(float4*)(Dm + (size_t)col * NN + rb) = make_float4(v0, v1, v2, v3);
      tmax = fmaxf(tmax, fmaxf(fmaxf(v0, v1), fmaxf(v2, v3)));
      float vv[4] = {v0, v1, v2, v3};
      #pragma unroll
      for (int rg = 0; rg < 4; ++rg) {
        int row = rb + rg;
        if (!diag || col != row) {
          unsigned lo = (row < col) ? (unsigned)(row * NN + col)
                                    : (unsigned)(col * NN + row);
          unsigned long long key =
              ((unsigned long long)__float_as_uint(vv[rg]) << 32) | lo;
          rk[mi][rg] = u64min(rk[mi][rg], key);
          ck[ni] = u64min(ck[ni], key);
        }
      }
    }
  }
  unsigned long long* b1 = best1 + (size_t)m * NN;
  #pragma unroll
  for (int mi = 0; mi < 4; ++mi)
    #pragma unroll
    for (int rg = 0; rg < 4; ++rg) {
      unsigned long long k = grp16_min_u64(rk[mi][rg]);
      if (lr == 15) atomicMin(&b1[gr0 + mi * 16 + lk * 4 + rg], k);
    }
  if (!diag) {
    #pragma unroll
    for (int ni = 0; ni < 4; ++ni) {
      unsigned long long k = ck[ni];
      k = u64min(k, __shfl_xor(k, 16));
      k = u64min(k, __shfl_xor(k, 32));
      if (lk == 0) atomicMin(&b1[gc0 + ni * 16 + lr], k);
    }
  }
  #pragma unroll
  for (int off = 32; off > 0; off >>= 1) tmax = fmaxf(tmax, __shfl_down(tmax, off));
  if (lane == 0) atomicMax(&maxBits[m], __float_as_uint(tmax));
}

// -------- phase-1 hook (comp = identity), emit edges, write comp labels ---------
__global__ __launch_bounds__(512) void hook1_kernel(const unsigned long long* __restrict__ best1,
                                                    int* __restrict__ compG,
                                                    int2* __restrict__ eo_all,
                                                    int* __restrict__ ecntG, int m0) {
  int mL = blockIdx.x, m = m0 + mL;
  const unsigned long long* b1 = best1 + (size_t)m * NN;
  int2* eo = eo_all + (size_t)m * (NN - 1);
  __shared__ int hook[NN], parent[NN];
  __shared__ int ecnt;
  int tid = threadIdx.x;
  if (tid == 0) ecnt = 0;
  unsigned long long b = b1[tid];
  int h;
  if (b != ~0ull) {
    int idx = (int)(unsigned)b;
    int er = idx >> 9, ec = idx & 511;
    h = (er == tid) ? ec : er;
  } else h = tid;
  hook[tid] = h;
  __syncthreads();
  bool active = (b != ~0ull);
  int p = h;
  bool mutual = active && (hook[p] == tid);
  parent[tid] = (!active) ? tid : ((mutual && tid < p) ? tid : p);
  if (active && (!mutual || tid > p)) {
    int idx = (int)(unsigned)b;
    int e = atomicAdd(&ecnt, 1);
    eo[e] = make_int2(idx >> 9, idx & 511);
  }
  __syncthreads();
  int c = tid, pp = parent[c];
  while (pp != c) { c = pp; pp = parent[c]; }
  compG[(size_t)m * NN + tid] = c;
  if (tid == 0) ecntG[m] = ecnt;
}

// -------- phase-2 scan: 8 blocks/matrix, wave-per-row, atomicMin per comp -------
__global__ __launch_bounds__(512) void scan2_kernel(const float* __restrict__ Dreg,
                                                    const int* __restrict__ compG,
                                                    unsigned long long* __restrict__ best2,
                                                    int m0) {
  int sblk = blockIdx.x, mL = blockIdx.y, m = m0 + mL;
  const float* D = Dreg + (size_t)mL * NN2;
  __shared__ int compP[NN + 64];
  int tid = threadIdx.x;
  int wave = tid >> 6, lane = tid & 63;
  int c0 = lane * 8;
  if (tid < NN) compP[tid + (tid >> 3)] = compG[(size_t)m * NN + tid];
  __syncthreads();
  unsigned long long* b2 = best2 + (size_t)m * NN;
  #pragma unroll
  for (int rr = 0; rr < 8; ++rr) {
    int r = sblk * 64 + wave * 8 + rr;
    int cr = compP[r + (r >> 3)];
    const float4* rp = (const float4*)(D + (size_t)r * NN + c0);
    float4 v0 = rp[0], v1 = rp[1];
    int4 cc0 = *(const int4*)(compP + c0 + (c0 >> 3));
    int4 cc1 = *(const int4*)(compP + c0 + 4 + (c0 >> 3));
    float vv[8] = {v0.x, v0.y, v0.z, v0.w, v1.x, v1.y, v1.z, v1.w};
    int cv[8] = {cc0.x, cc0.y, cc0.z, cc0.w, cc1.x, cc1.y, cc1.z, cc1.w};
    unsigned long long k = ~0ull;
    #pragma unroll
    for (int e = 0; e < 8; ++e) {
      if (cv[e] != cr) {
        int col = c0 + e;
        int lo = (r < col) ? r * NN + col : col * NN + r;
        unsigned long long key = ((unsigned long long)__float_as_uint(vv[e]) << 32) | (unsigned)lo;
        k = u64min(k, key);
      }
    }
    k = wave_min_u64(k);
    if (lane == 63 && k != ~0ull) atomicMin(&b2[cr], k);
  }
}

// -------- phase-2 hook + dense remap (C <= 128 guaranteed) ----------------------
__global__ __launch_bounds__(512) void hook2_kernel(const unsigned long long* __restrict__ best2,
                                                    const int* __restrict__ compG,
                                                    int* __restrict__ comp2g,
                                                    int2* __restrict__ eo_all,
                                                    int* __restrict__ ecntG,
                                                    int* __restrict__ cntG, int m0) {
  int mL = blockIdx.x, m = m0 + mL;
  const unsigned long long* b2 = best2 + (size_t)m * NN;
  int2* eo = eo_all + (size_t)m * (NN - 1);
  __shared__ int comp[NN], hook[NN], parent[NN], dmap[NN];
  __shared__ int ecnt, ccnt;
  int tid = threadIdx.x;
  if (tid == 0) { ecnt = ecntG[m]; ccnt = 0; }
  comp[tid] = compG[(size_t)m * NN + tid];
  __syncthreads();
  unsigned long long b = b2[tid];
  int h;
  if (b != ~0ull) {
    int idx = (int)(unsigned)b;
    int er = idx >> 9, ec = idx & 511;
    int c1 = comp[er], c2 = comp[ec];
    h = (c1 == tid) ? c2 : c1;
  } else h = tid;
  hook[tid] = h;
  __syncthreads();
  bool active = (b != ~0ull);
  int p = h;
  bool mutual = active && (hook[p] == tid);
  parent[tid] = (!active) ? tid : ((mutual && tid < p) ? tid : p);
  if (active && (!mutual || tid > p)) {
    int idx = (int)(unsigned)b;
    int e = atomicAdd(&ecnt, 1);
    eo[e] = make_int2(idx >> 9, idx & 511);
  }
  __syncthreads();
  int c = comp[tid], pp = parent[c];
  while (pp != c) { c = pp; pp = parent[c]; }
  __syncthreads();
  comp[tid] = c;
  __syncthreads();
  if (comp[tid] == tid) dmap[tid] = atomicAdd(&ccnt, 1);
  __syncthreads();
  comp2g[(size_t)m * NN + tid] = dmap[comp[tid]];
  if (tid == 0) { ecntG[m] = ecnt; cntG[m] = ccnt; }
}

// -------- contraction: 4 blocks/matrix build LDS-partial Dc, merge to global ----
__global__ __launch_bounds__(512) void contract_kernel(const float* __restrict__ Dreg,
                                                       const int* __restrict__ comp2g,
                                                       unsigned long long* __restrict__ DcG,
                                                       int m0) {
  int q = blockIdx.x, mL = blockIdx.y, m = m0 + mL;
  const float* D = Dreg + (size_t)mL * NN2;
  __shared__ unsigned long long Dc[128 * 128];
  __shared__ int c2P[NN + 64];
  int tid = threadIdx.x;
  int wave = tid >> 6, lane = tid & 63;
  int c0 = lane * 8;
  if (tid < NN) c2P[tid + (tid >> 3)] = comp2g[(size_t)m * NN + tid];
  for (int i = tid; i < 16384; i += 512) Dc[i] = ~0ull;
  __syncthreads();
  #pragma unroll
  for (int rr = 0; rr < 16; ++rr) {
    int r = q * 128 + wave * 16 + rr;
    int di = c2P[r + (r >> 3)];
    const float4* rp = (const float4*)(D + (size_t)r * NN + c0);
    float4 v0 = rp[0], v1 = rp[1];
    int4 cc0 = *(const int4*)(c2P + c0 + (c0 >> 3));
    int4 cc1 = *(const int4*)(c2P + c0 + 4 + (c0 >> 3));
    float vv[8] = {v0.x, v0.y, v0.z, v0.w, v1.x, v1.y, v1.z, v1.w};
    int cv[8] = {cc0.x, cc0.y, cc0.z, cc0.w, cc1.x, cc1.y, cc1.z, cc1.w};
    #pragma unroll
    for (int e = 0; e < 8; ++e) {
      if (cv[e] != di) {
        int col = c0 + e;
        int lo = (r < col) ? r * NN + col : col * NN + r;
        unsigned long long key = ((unsigned long long)__float_as_uint(vv[e]) << 32) | (unsigned)lo;
        amin64(&Dc[di * 128 + cv[e]], key);
      }
    }
  }
  __syncthreads();
  unsigned long long* dg = DcG + (size_t)mL * 16384;
  for (int i = tid; i < 16384; i += 512) {
    unsigned long long v = Dc[i];
    if (v != ~0ull) atomicMin(&dg[i], v);
  }
}

// -------- finish: LDS-resident phases on contracted matrix + fused gather -------
__global__ __launch_bounds__(1024) void finish_kernel(const float* __restrict__ Dreg,
                                                      const unsigned long long* __restrict__ DcG,
                                                      const int* __restrict__ comp2g,
                                                      const int* __restrict__ cntG,
                                                      int2* __restrict__ eo_all,
                                                      int* __restrict__ ecntG,
                                                      const unsigned* __restrict__ maxBits,
                                                      float* __restrict__ out, int m0) {
  int mL = blockIdx.x, m = m0 + mL;
  __shared__ unsigned long long Dc[16384];
  __shared__ int c2n[NN];
  __shared__ unsigned long long best[128];
  __shared__ int comp2[128], hook128[128], parent128[128];
  __shared__ float fred[16];
  __shared__ int ecnt;
  int tid = threadIdx.x;
  int wave = tid >> 6, lane = tid & 63;
  const unsigned long long* dg = DcG + (size_t)mL * 16384;
  for (int i = tid; i < 16384; i += 1024) Dc[i] = dg[i];
  if (tid < NN) c2n[tid] = comp2g[(size_t)m * NN + tid];
  if (tid < 128) comp2[tid] = tid;
  if (tid == 0) ecnt = ecntG[m];
  __syncthreads();
  int C = cntG[m];
  int2* eo = eo_all + (size_t)m * (NN - 1);

  for (int ph = 0; ph < 7; ++ph) {
    if (ecnt >= NN - 1) break;
    if (tid < 128) best[tid] = ~0ull;
    __syncthreads();
    for (int i = tid; i < C * 128; i += 1024) {
      unsigned long long key = Dc[i];
      if (key == ~0ull) continue;
      int a = i >> 7, bb = i & 127;
      int ca = comp2[a], cb = comp2[bb];
      if (ca != cb) amin64(&best[ca], key);
    }
    __syncthreads();
    if (tid < C) {
      unsigned long long b = best[tid];
      int h;
      if (b != ~0ull) {
        int pid = (int)(unsigned)b;
        int er = pid >> 9, ec = pid & 511;
        int c1 = comp2[c2n[er]], c2v = comp2[c2n[ec]];
        h = (c1 == tid) ? c2v : c1;
      } else h = tid;
      hook128[tid] = h;
    }
    __syncthreads();
    if (tid < C) {
      unsigned long long b = best[tid];
      bool active = (b != ~0ull);
      int p = hook128[tid];
      bool mutual = active && (hook128[p] == tid);
      parent128[tid] = (!active) ? tid : ((mutual && tid < p) ? tid : p);
      if (active && (!mutual || tid > p)) {
        int pid = (int)(unsigned)b;
        int e = atomicAdd(&ecnt, 1);
        eo[e] = make_int2(pid >> 9, pid & 511);
      }
    }
    __syncthreads();
    if (tid < C) {
      int c = comp2[tid], pp = parent128[c];
      while (pp != c) { c = pp; pp = parent128[c]; }
      comp2[tid] = c;
    }
    __syncthreads();
  }
  __syncthreads();

  // fused loss gather
  int b = m >> 1;
  float mxX = fmaxf(__uint_as_float(maxBits[2 * b]), 1e-12f);
  float mxZ = fmaxf(__uint_as_float(maxBits[2 * b + 1]), 1e-12f);
  float rX = 1.0f / mxX, rZ = 1.0f / mxZ;
  const float* Dx = Dreg + (size_t)(mL & ~1) * NN2;
  const float* Dz = Dx + NN2;
  float acc = 0.f;
  if (tid < NN - 1) {
    int2 e = eo[tid];
    size_t off = (size_t)e.x * NN + e.y;
    float d = Dx[off] * rX - Dz[off] * rZ;
    acc = d * d;
  }
  #pragma unroll
  for (int o = 32; o > 0; o >>= 1) acc += __shfl_down(acc, o);
  if (lane == 0) fred[wave] = acc;
  __syncthreads();
  if (tid == 0) {
    float t = 0.f;
    #pragma unroll
    for (int i = 0; i < 16; ++i) t += fred[i];
    atomicAdd(out, t * (1.0f / NB));
  }
}

extern "C" void kernel_launch(void* const* d_in, const int* in_sizes, int n_in,
                              void* d_out, int out_size, void* d_ws, size_t ws_size,
                              hipStream_t stream) {
  const float* model = (const float*)d_in[0];
  const float* labels = (const float*)d_in[1];
  float* out = (float*)d_out;
  char* ws = (char*)d_ws;

  float*              sq      = (float*)(ws);                       // 131072
  unsigned*           maxBits = (unsigned*)(ws + 131072);           // -> 132096
  int2*               eo      = (int2*)(ws + 132096);               // -> 393728
  unsigned long long* best1   = (unsigned long long*)(ws + 393728); // -> 655872
  unsigned long long* best2   = (unsigned long long*)(ws + 655872); // -> 918016
  int*                compG   = (int*)(ws + 918016);                // -> 1049088
  int*                comp2g  = (int*)(ws + 1049088);               // -> 1180160
  int*                ecntG   = (int*)(ws + 1180160);               // -> 1180416
  int*                cntG    = (int*)(ws + 1180416);               // -> 1180672
  size_t base = 1181696;

  // per batch (2 matrices): D 2MB + Hi 1MB + Lo 1MB + Dc 256KB
  size_t perBatch = 2ull * (NN2 * sizeof(float) + 2ull * NN2 * 2 + 16384 * 8);
  size_t dcap = (ws_size > base) ? (ws_size - base) : 0;
  int cb = (int)(dcap / perBatch);
  if (cb > NB) cb = NB;
  if (cb < 1) cb = 1;
  int nmc = 2 * cb;

  float* Dreg = (float*)(ws + base);
  unsigned short* Hi = (unsigned short*)(ws + base + (size_t)nmc * NN2 * sizeof(float));
  unsigned short* Lo = Hi + (size_t)nmc * NN2;
  unsigned long long* DcG = (unsigned long long*)(Lo + (size_t)nmc * NN2);

  hipMemsetAsync(d_out, 0, sizeof(float), stream);
  hipMemsetAsync(maxBits, 0, 64 * sizeof(unsigned), stream);

  for (int b0 = 0; b0 < NB; b0 += cb) {
    int nb = (NB - b0 < cb) ? (NB - b0) : cb;
    int nm = 2 * nb, m0 = 2 * b0;
    hipMemsetAsync(best1 + (size_t)m0 * NN, 0xFF, (size_t)nm * NN * 8, stream);
    hipMemsetAsync(best2 + (size_t)m0 * NN, 0xFF, (size_t)nm * NN * 8, stream);
    hipMemsetAsync(DcG, 0xFF, (size_t)nm * 16384 * 8, stream);
    split_kernel<<<nm * 256, 256, 0, stream>>>(model, labels, Hi, Lo, sq, m0);
    gemm_dist<<<10 * nm, 256, 0, stream>>>(Hi, Lo, sq, Dreg, maxBits, best1, m0, nm);
    hook1_kernel<<<nm, 512, 0, stream>>>(best1, compG, eo, ecntG, m0);
    scan2_kernel<<<dim3(8, nm), 512, 0, stream>>>(Dreg, compG, best2, m0);
    hook2_kernel<<<nm, 512, 0, stream>>>(best2, compG, comp2g, eo, ecntG, cntG, m0);
    contract_kernel<<<dim3(4, nm), 512, 0, stream>>>(Dreg, comp2g, DcG, m0);
    finish_kernel<<<nm, 1024, 0, stream>>>(Dreg, DcG, comp2g, cntG, eo, ecntG,
                                           maxBits, out, m0);
  }
}

// Round 13
// 149.193 us; speedup vs baseline: 1.4934x; 1.0951x over previous
//
#include <hip/hip_runtime.h>
#include <math.h>

#define NN 512
#define NN2 (NN*NN)
#define NB 32
#define NM 64

typedef __attribute__((ext_vector_type(8))) short short8v;   // 8 bf16 (4 VGPR)
typedef __attribute__((ext_vector_type(4))) float f32x4;     // MFMA acc

typedef const unsigned int __attribute__((address_space(1)))* gas_ptr;
typedef unsigned int __attribute__((address_space(3)))* las_ptr;

__device__ __forceinline__ float sigm(float x) { return 1.0f / (1.0f + expf(-x)); }

__device__ __forceinline__ unsigned short f2bf(float x) {
  unsigned u = __float_as_uint(x);
  return (unsigned short)((u + 0x7fffu + ((u >> 16) & 1u)) >> 16);   // RNE
}
__device__ __forceinline__ float bf2f(unsigned short h) {
  return __uint_as_float(((unsigned)h) << 16);
}
__device__ __forceinline__ unsigned long long u64min(unsigned long long a,
                                                     unsigned long long b) {
  return (b < a) ? b : a;
}
__device__ __forceinline__ void amin64(unsigned long long* p, unsigned long long v) {
  unsigned long long old = *p;
  while (v < old) {
    unsigned long long assumed = old;
    old = atomicCAS(p, assumed, v);
    if (old == assumed) break;
  }
}
template <int CTRL>
__device__ __forceinline__ unsigned long long dpp_min_u64(unsigned long long x) {
  int xlo = (int)(unsigned)x, xhi = (int)(unsigned)(x >> 32);
  int ylo = __builtin_amdgcn_update_dpp(xlo, xlo, CTRL, 0xf, 0xf, false);
  int yhi = __builtin_amdgcn_update_dpp(xhi, xhi, CTRL, 0xf, 0xf, false);
  unsigned long long y = ((unsigned long long)(unsigned)yhi << 32) | (unsigned)ylo;
  return (y < x) ? y : x;
}
__device__ __forceinline__ unsigned long long wave_min_u64(unsigned long long k) {
  k = dpp_min_u64<0x111>(k); k = dpp_min_u64<0x112>(k);
  k = dpp_min_u64<0x114>(k); k = dpp_min_u64<0x118>(k);
  k = dpp_min_u64<0x142>(k); k = dpp_min_u64<0x143>(k);
  return k;
}
__device__ __forceinline__ unsigned long long grp16_min_u64(unsigned long long k) {
  k = dpp_min_u64<0x111>(k); k = dpp_min_u64<0x112>(k);
  k = dpp_min_u64<0x114>(k); k = dpp_min_u64<0x118>(k);
  return k;
}

// -------- sigmoid + bf16 hi/lo split + fused row sums-of-squares ----------------
__global__ __launch_bounds__(256) void split_kernel(const float* __restrict__ model,
                                                    const float* __restrict__ labels,
                                                    unsigned short* __restrict__ Hi,
                                                    unsigned short* __restrict__ Lo,
                                                    float* __restrict__ sq, int m0) {
  int b = blockIdx.x;
  int mL = b >> 8;
  int m = m0 + mL;
  int tid = threadIdx.x;
  size_t off = (size_t)(b & 255) * 1024 + tid * 4;
  const float* src = ((m & 1) ? labels + (size_t)(m >> 1) * NN2
                              : model + (size_t)(m >> 1) * NN2) + off;
  float4 v = *(const float4*)src;
  if (!(m & 1)) { v.x = sigm(v.x); v.y = sigm(v.y); v.z = sigm(v.z); v.w = sigm(v.w); }
  ushort4 h, l;
  h.x = f2bf(v.x); l.x = f2bf(v.x - bf2f(h.x));
  h.y = f2bf(v.y); l.y = f2bf(v.y - bf2f(h.y));
  h.z = f2bf(v.z); l.z = f2bf(v.z - bf2f(h.z));
  h.w = f2bf(v.w); l.w = f2bf(v.w - bf2f(h.w));
  *(ushort4*)(Hi + (size_t)mL * NN2 + off) = h;
  *(ushort4*)(Lo + (size_t)mL * NN2 + off) = l;
  float s = v.x * v.x + v.y * v.y + v.z * v.z + v.w * v.w;
  #pragma unroll
  for (int o = 32; o > 0; o >>= 1) s += __shfl_down(s, o);
  __shared__ float red[4];
  if ((tid & 63) == 0) red[tid >> 6] = s;
  __syncthreads();
  if (tid == 0) {
    int row0 = (b & 255) * 2;
    sq[(size_t)m * NN + row0]     = red[0] + red[1];
    sq[(size_t)m * NN + row0 + 1] = red[2] + red[3];
  }
}

// ------- distance matrix: 3-pass split-bf16 MFMA, global_load_lds staging,
//         register-lean frag scheduling + per-mi key reduction (occupancy) ------
__global__ __launch_bounds__(256, 3) void gemm_dist(const unsigned short* __restrict__ Hi,
                                                    const unsigned short* __restrict__ Lo,
                                                    const float* __restrict__ sq,
                                                    float* __restrict__ Dreg,
                                                    unsigned* __restrict__ maxBits,
                                                    unsigned long long* __restrict__ best1,
                                                    int m0, int nm) {
  __shared__ unsigned short P[4][128 * 32];   // Ah, Al, Bh, Bl (8 KB each)
  // XCD-aware decode: blocks of one matrix land on one XCD (id%8 = XCD)
  int id = blockIdx.x;
  int p, mL;
  if ((nm & 7) == 0) {
    int x = id & 7, t = id >> 3;
    p = t % 10;
    mL = x + 8 * (t / 10);
  } else {
    p = id % 10;
    mL = id / 10;
  }
  int by = (p >= 4) + (p >= 7) + (p >= 9);
  int bx = p - ((by * (7 - by)) >> 1);
  bool diag = (by == bx);
  int m = m0 + mL;
  const unsigned short* Hm = Hi + (size_t)mL * NN2;
  const unsigned short* Lm = Lo + (size_t)mL * NN2;

  int tid = threadIdx.x;
  int wid = tid >> 6, lane = tid & 63;
  int wy = wid >> 1, wx = wid & 1;    // 2x2 waves of 64x64
  int lr = lane & 15, lk = lane >> 4;

  // staging: wave wid owns panel wid (Ah,Al,Bh,Bl); diag blocks skip B panels
  const unsigned short* wsrcM = (wid & 1) ? Lm : Hm;
  int wrow0 = (wid < 2) ? by * 128 : bx * 128;
  bool stage = (!diag) || (wid < 2);
  int srow = lane >> 2;
  int schunk = (lane & 3) ^ ((lane >> 3) & 3);
  const unsigned short* gsrc = wsrcM + (size_t)(wrow0 + srow) * NN + schunk * 8;
  unsigned short* ldst = &P[wid & 3][0];

  f32x4 acc[4][4];
  #pragma unroll
  for (int i = 0; i < 4; ++i)
    #pragma unroll
    for (int j = 0; j < 4; ++j) acc[i][j] = (f32x4){0.f, 0.f, 0.f, 0.f};

  const unsigned short* bAh = &P[0][0];
  const unsigned short* bAl = &P[1][0];
  const unsigned short* bBh = diag ? &P[0][0] : &P[2][0];
  const unsigned short* bBl = diag ? &P[1][0] : &P[3][0];
  int sw = (lr >> 1) & 3;                         // read-side swizzle (lane-only)
  int rao = (wy * 64 + lr) * 32 + (lk ^ sw) * 8;  // A frag base index (panel shorts)
  int rbo = (wx * 64 + lr) * 32 + (lk ^ sw) * 8;  // B frag base index

  for (int s = 0; s < 16; ++s) {
    int k0 = s * 32;
    if (stage) {
      #pragma unroll
      for (int i = 0; i < 8; ++i)
        __builtin_amdgcn_global_load_lds(
            (gas_ptr)(const void*)(gsrc + k0 + (size_t)i * 16 * NN),
            (las_ptr)(void*)(ldst + i * 512), 16, 0, 0);
    }
    __syncthreads();                 // drains vmcnt: panels landed

    // register-lean frag scheduling: max 12 frags live (48 VGPR)
    short8v fa[4], fb[4], fb2[4];
    #pragma unroll
    for (int i = 0; i < 4; ++i) {
      fa[i] = *(const short8v*)(bAh + rao + i * 16 * 32);   // Ah
      fb[i] = *(const short8v*)(bBh + rbo + i * 16 * 32);   // Bh
    }
    #pragma unroll
    for (int mi = 0; mi < 4; ++mi)
      #pragma unroll
      for (int ni = 0; ni < 4; ++ni)
        acc[mi][ni] = __builtin_amdgcn_mfma_f32_16x16x32_bf16(fa[mi], fb[ni], acc[mi][ni], 0, 0, 0);
    #pragma unroll
    for (int i = 0; i < 4; ++i)
      fb2[i] = *(const short8v*)(bBl + rbo + i * 16 * 32);  // Bl
    #pragma unroll
    for (int mi = 0; mi < 4; ++mi)
      #pragma unroll
      for (int ni = 0; ni < 4; ++ni)
        acc[mi][ni] = __builtin_amdgcn_mfma_f32_16x16x32_bf16(fa[mi], fb2[ni], acc[mi][ni], 0, 0, 0);
    #pragma unroll
    for (int i = 0; i < 4; ++i)
      fa[i] = *(const short8v*)(bAl + rao + i * 16 * 32);   // Al (overwrites Ah)
    #pragma unroll
    for (int mi = 0; mi < 4; ++mi)
      #pragma unroll
      for (int ni = 0; ni < 4; ++ni)
        acc[mi][ni] = __builtin_amdgcn_mfma_f32_16x16x32_bf16(fa[mi], fb[ni], acc[mi][ni], 0, 0, 0);
    __syncthreads();                 // all frag reads done before next overwrite
  }

  const float* sqm = sq + (size_t)m * NN;
  float* Dm = Dreg + (size_t)mL * NN2;
  int gr0 = by * 128 + wy * 64;
  int gc0 = bx * 128 + wx * 64;
  float tmax = 0.f;
  unsigned long long* b1 = best1 + (size_t)m * NN;
  unsigned long long ck[4];
  #pragma unroll
  for (int i = 0; i < 4; ++i) ck[i] = ~0ull;

  // per-mi processing: rk live range is one mi-iteration (8 VGPR, not 32)
  #pragma unroll
  for (int mi = 0; mi < 4; ++mi) {
    int rb = gr0 + mi * 16 + lk * 4;
    float sqi0 = sqm[rb + 0], sqi1 = sqm[rb + 1], sqi2 = sqm[rb + 2], sqi3 = sqm[rb + 3];
    unsigned long long rk[4];
    #pragma unroll
    for (int j = 0; j < 4; ++j) rk[j] = ~0ull;
    #pragma unroll
    for (int ni = 0; ni < 4; ++ni) {
      int col = gc0 + ni * 16 + lr;
      float sqj = sqm[col];
      f32x4 a = acc[mi][ni];
      float v0 = sqrtf(fmaxf(sqi0 + sqj - 2.f * a[0], 0.f));
      float v1 = sqrtf(fmaxf(sqi1 + sqj - 2.f * a[1], 0.f));
      float v2 = sqrtf(fmaxf(sqi2 + sqj - 2.f * a[2], 0.f));
      float v3 = sqrtf(fmaxf(sqi3 + sqj - 2.f * a[3], 0.f));
      Dm[(size_t)(rb + 0) * NN + col] = v0;
      Dm[(size_t)(rb + 1) * NN + col] = v1;
      Dm[(size_t)(rb + 2) * NN + col] = v2;
      Dm[(size_t)(rb + 3) * NN + col] = v3;
      if (!diag)
        *(float4*)(Dm + (size_t)col * NN + rb) = make_float4(v0, v1, v2, v3);
      tmax = fmaxf(tmax, fmaxf(fmaxf(v0, v1), fmaxf(v2, v3)));
      float vv[4] = {v0, v1, v2, v3};
      #pragma unroll
      for (int rg = 0; rg < 4; ++rg) {
        int row = rb + rg;
        if (!diag || col != row) {
          unsigned lo = (row < col) ? (unsigned)(row * NN + col)
                                    : (unsigned)(col * NN + row);
          unsigned long long key =
              ((unsigned long long)__float_as_uint(vv[rg]) << 32) | lo;
          rk[rg] = u64min(rk[rg], key);
          ck[ni] = u64min(ck[ni], key);
        }
      }
    }
    #pragma unroll
    for (int rg = 0; rg < 4; ++rg) {
      unsigned long long k = grp16_min_u64(rk[rg]);
      if (lr == 15) atomicMin(&b1[rb + rg], k);
    }
  }
  if (!diag) {
    #pragma unroll
    for (int ni = 0; ni < 4; ++ni) {
      unsigned long long k = ck[ni];
      k = u64min(k, __shfl_xor(k, 16));
      k = u64min(k, __shfl_xor(k, 32));
      if (lk == 0) atomicMin(&b1[gc0 + ni * 16 + lr], k);
    }
  }
  #pragma unroll
  for (int off = 32; off > 0; off >>= 1) tmax = fmaxf(tmax, __shfl_down(tmax, off));
  if (lane == 0) atomicMax(&maxBits[m], __float_as_uint(tmax));
}

// -------- phase-1 hook (comp = identity), emit edges, write comp labels ---------
__global__ __launch_bounds__(512) void hook1_kernel(const unsigned long long* __restrict__ best1,
                                                    int* __restrict__ compG,
                                                    int2* __restrict__ eo_all,
                                                    int* __restrict__ ecntG, int m0) {
  int mL = blockIdx.x, m = m0 + mL;
  const unsigned long long* b1 = best1 + (size_t)m * NN;
  int2* eo = eo_all + (size_t)m * (NN - 1);
  __shared__ int hook[NN], parent[NN];
  __shared__ int ecnt;
  int tid = threadIdx.x;
  if (tid == 0) ecnt = 0;
  unsigned long long b = b1[tid];
  int h;
  if (b != ~0ull) {
    int idx = (int)(unsigned)b;
    int er = idx >> 9, ec = idx & 511;
    h = (er == tid) ? ec : er;
  } else h = tid;
  hook[tid] = h;
  __syncthreads();
  bool active = (b != ~0ull);
  int p = h;
  bool mutual = active && (hook[p] == tid);
  parent[tid] = (!active) ? tid : ((mutual && tid < p) ? tid : p);
  if (active && (!mutual || tid > p)) {
    int idx = (int)(unsigned)b;
    int e = atomicAdd(&ecnt, 1);
    eo[e] = make_int2(idx >> 9, idx & 511);
  }
  __syncthreads();
  int c = tid, pp = parent[c];
  while (pp != c) { c = pp; pp = parent[c]; }
  compG[(size_t)m * NN + tid] = c;
  if (tid == 0) ecntG[m] = ecnt;
}

// -------- phase-2 scan: 8 blocks/matrix, wave-per-row, atomicMin per comp -------
__global__ __launch_bounds__(512) void scan2_kernel(const float* __restrict__ Dreg,
                                                    const int* __restrict__ compG,
                                                    unsigned long long* __restrict__ best2,
                                                    int m0) {
  int sblk = blockIdx.x, mL = blockIdx.y, m = m0 + mL;
  const float* D = Dreg + (size_t)mL * NN2;
  __shared__ int compP[NN + 64];
  int tid = threadIdx.x;
  int wave = tid >> 6, lane = tid & 63;
  int c0 = lane * 8;
  if (tid < NN) compP[tid + (tid >> 3)] = compG[(size_t)m * NN + tid];
  __syncthreads();
  unsigned long long* b2 = best2 + (size_t)m * NN;
  #pragma unroll
  for (int rr = 0; rr < 8; ++rr) {
    int r = sblk * 64 + wave * 8 + rr;
    int cr = compP[r + (r >> 3)];
    const float4* rp = (const float4*)(D + (size_t)r * NN + c0);
    float4 v0 = rp[0], v1 = rp[1];
    int4 cc0 = *(const int4*)(compP + c0 + (c0 >> 3));
    int4 cc1 = *(const int4*)(compP + c0 + 4 + (c0 >> 3));
    float vv[8] = {v0.x, v0.y, v0.z, v0.w, v1.x, v1.y, v1.z, v1.w};
    int cv[8] = {cc0.x, cc0.y, cc0.z, cc0.w, cc1.x, cc1.y, cc1.z, cc1.w};
    unsigned long long k = ~0ull;
    #pragma unroll
    for (int e = 0; e < 8; ++e) {
      if (cv[e] != cr) {
        int col = c0 + e;
        int lo = (r < col) ? r * NN + col : col * NN + r;
        unsigned long long key = ((unsigned long long)__float_as_uint(vv[e]) << 32) | (unsigned)lo;
        k = u64min(k, key);
      }
    }
    k = wave_min_u64(k);
    if (lane == 63 && k != ~0ull) atomicMin(&b2[cr], k);
  }
}

// -------- phase-2 hook + dense remap (C <= 128 guaranteed) ----------------------
__global__ __launch_bounds__(512) void hook2_kernel(const unsigned long long* __restrict__ best2,
                                                    const int* __restrict__ compG,
                                                    int* __restrict__ comp2g,
                                                    int2* __restrict__ eo_all,
                                                    int* __restrict__ ecntG,
                                                    int* __restrict__ cntG, int m0) {
  int mL = blockIdx.x, m = m0 + mL;
  const unsigned long long* b2 = best2 + (size_t)m * NN;
  int2* eo = eo_all + (size_t)m * (NN - 1);
  __shared__ int comp[NN], hook[NN], parent[NN], dmap[NN];
  __shared__ int ecnt, ccnt;
  int tid = threadIdx.x;
  if (tid == 0) { ecnt = ecntG[m]; ccnt = 0; }
  comp[tid] = compG[(size_t)m * NN + tid];
  __syncthreads();
  unsigned long long b = b2[tid];
  int h;
  if (b != ~0ull) {
    int idx = (int)(unsigned)b;
    int er = idx >> 9, ec = idx & 511;
    int c1 = comp[er], c2 = comp[ec];
    h = (c1 == tid) ? c2 : c1;
  } else h = tid;
  hook[tid] = h;
  __syncthreads();
  bool active = (b != ~0ull);
  int p = h;
  bool mutual = active && (hook[p] == tid);
  parent[tid] = (!active) ? tid : ((mutual && tid < p) ? tid : p);
  if (active && (!mutual || tid > p)) {
    int idx = (int)(unsigned)b;
    int e = atomicAdd(&ecnt, 1);
    eo[e] = make_int2(idx >> 9, idx & 511);
  }
  __syncthreads();
  int c = comp[tid], pp = parent[c];
  while (pp != c) { c = pp; pp = parent[c]; }
  __syncthreads();
  comp[tid] = c;
  __syncthreads();
  if (comp[tid] == tid) dmap[tid] = atomicAdd(&ccnt, 1);
  __syncthreads();
  comp2g[(size_t)m * NN + tid] = dmap[comp[tid]];
  if (tid == 0) { ecntG[m] = ecnt; cntG[m] = ccnt; }
}

// -------- contraction: 4 blocks/matrix build LDS-partial Dc, merge to global ----
__global__ __launch_bounds__(512) void contract_kernel(const float* __restrict__ Dreg,
                                                       const int* __restrict__ comp2g,
                                                       unsigned long long* __restrict__ DcG,
                                                       int m0) {
  int q = blockIdx.x, mL = blockIdx.y, m = m0 + mL;
  const float* D = Dreg + (size_t)mL * NN2;
  __shared__ unsigned long long Dc[128 * 128];
  __shared__ int c2P[NN + 64];
  int tid = threadIdx.x;
  int wave = tid >> 6, lane = tid & 63;
  int c0 = lane * 8;
  if (tid < NN) c2P[tid + (tid >> 3)] = comp2g[(size_t)m * NN + tid];
  for (int i = tid; i < 16384; i += 512) Dc[i] = ~0ull;
  __syncthreads();
  #pragma unroll
  for (int rr = 0; rr < 16; ++rr) {
    int r = q * 128 + wave * 16 + rr;
    int di = c2P[r + (r >> 3)];
    const float4* rp = (const float4*)(D + (size_t)r * NN + c0);
    float4 v0 = rp[0], v1 = rp[1];
    int4 cc0 = *(const int4*)(c2P + c0 + (c0 >> 3));
    int4 cc1 = *(const int4*)(c2P + c0 + 4 + (c0 >> 3));
    float vv[8] = {v0.x, v0.y, v0.z, v0.w, v1.x, v1.y, v1.z, v1.w};
    int cv[8] = {cc0.x, cc0.y, cc0.z, cc0.w, cc1.x, cc1.y, cc1.z, cc1.w};
    #pragma unroll
    for (int e = 0; e < 8; ++e) {
      if (cv[e] != di) {
        int col = c0 + e;
        int lo = (r < col) ? r * NN + col : col * NN + r;
        unsigned long long key = ((unsigned long long)__float_as_uint(vv[e]) << 32) | (unsigned)lo;
        amin64(&Dc[di * 128 + cv[e]], key);
      }
    }
  }
  __syncthreads();
  unsigned long long* dg = DcG + (size_t)mL * 16384;
  for (int i = tid; i < 16384; i += 512) {
    unsigned long long v = Dc[i];
    if (v != ~0ull) atomicMin(&dg[i], v);
  }
}

// -------- finish: LDS-resident phases on contracted matrix + fused gather -------
__global__ __launch_bounds__(1024) void finish_kernel(const float* __restrict__ Dreg,
                                                      const unsigned long long* __restrict__ DcG,
                                                      const int* __restrict__ comp2g,
                                                      const int* __restrict__ cntG,
                                                      int2* __restrict__ eo_all,
                                                      int* __restrict__ ecntG,
                                                      const unsigned* __restrict__ maxBits,
                                                      float* __restrict__ out, int m0) {
  int mL = blockIdx.x, m = m0 + mL;
  __shared__ unsigned long long Dc[16384];
  __shared__ int c2n[NN];
  __shared__ unsigned long long best[128];
  __shared__ int comp2[128], hook128[128], parent128[128];
  __shared__ float fred[16];
  __shared__ int ecnt;
  int tid = threadIdx.x;
  int wave = tid >> 6, lane = tid & 63;
  const unsigned long long* dg = DcG + (size_t)mL * 16384;
  for (int i = tid; i < 16384; i += 1024) Dc[i] = dg[i];
  if (tid < NN) c2n[tid] = comp2g[(size_t)m * NN + tid];
  if (tid < 128) comp2[tid] = tid;
  if (tid == 0) ecnt = ecntG[m];
  __syncthreads();
  int C = cntG[m];
  int2* eo = eo_all + (size_t)m * (NN - 1);

  for (int ph = 0; ph < 7; ++ph) {
    if (ecnt >= NN - 1) break;
    if (tid < 128) best[tid] = ~0ull;
    __syncthreads();
    for (int i = tid; i < C * 128; i += 1024) {
      unsigned long long key = Dc[i];
      if (key == ~0ull) continue;
      int a = i >> 7, bb = i & 127;
      int ca = comp2[a], cb = comp2[bb];
      if (ca != cb) amin64(&best[ca], key);
    }
    __syncthreads();
    if (tid < C) {
      unsigned long long b = best[tid];
      int h;
      if (b != ~0ull) {
        int pid = (int)(unsigned)b;
        int er = pid >> 9, ec = pid & 511;
        int c1 = comp2[c2n[er]], c2v = comp2[c2n[ec]];
        h = (c1 == tid) ? c2v : c1;
      } else h = tid;
      hook128[tid] = h;
    }
    __syncthreads();
    if (tid < C) {
      unsigned long long b = best[tid];
      bool active = (b != ~0ull);
      int p = hook128[tid];
      bool mutual = active && (hook128[p] == tid);
      parent128[tid] = (!active) ? tid : ((mutual && tid < p) ? tid : p);
      if (active && (!mutual || tid > p)) {
        int pid = (int)(unsigned)b;
        int e = atomicAdd(&ecnt, 1);
        eo[e] = make_int2(pid >> 9, pid & 511);
      }
    }
    __syncthreads();
    if (tid < C) {
      int c = comp2[tid], pp = parent128[c];
      while (pp != c) { c = pp; pp = parent128[c]; }
      comp2[tid] = c;
    }
    __syncthreads();
  }
  __syncthreads();

  // fused loss gather
  int b = m >> 1;
  float mxX = fmaxf(__uint_as_float(maxBits[2 * b]), 1e-12f);
  float mxZ = fmaxf(__uint_as_float(maxBits[2 * b + 1]), 1e-12f);
  float rX = 1.0f / mxX, rZ = 1.0f / mxZ;
  const float* Dx = Dreg + (size_t)(mL & ~1) * NN2;
  const float* Dz = Dx + NN2;
  float acc = 0.f;
  if (tid < NN - 1) {
    int2 e = eo[tid];
    size_t off = (size_t)e.x * NN + e.y;
    float d = Dx[off] * rX - Dz[off] * rZ;
    acc = d * d;
  }
  #pragma unroll
  for (int o = 32; o > 0; o >>= 1) acc += __shfl_down(acc, o);
  if (lane == 0) fred[wave] = acc;
  __syncthreads();
  if (tid == 0) {
    float t = 0.f;
    #pragma unroll
    for (int i = 0; i < 16; ++i) t += fred[i];
    atomicAdd(out, t * (1.0f / NB));
  }
}

extern "C" void kernel_launch(void* const* d_in, const int* in_sizes, int n_in,
                              void* d_out, int out_size, void* d_ws, size_t ws_size,
                              hipStream_t stream) {
  const float* model = (const float*)d_in[0];
  const float* labels = (const float*)d_in[1];
  float* out = (float*)d_out;
  char* ws = (char*)d_ws;

  float*              sq      = (float*)(ws);                       // 131072
  unsigned*           maxBits = (unsigned*)(ws + 131072);           // -> 132096
  int2*               eo      = (int2*)(ws + 132096);               // -> 393728
  unsigned long long* best1   = (unsigned long long*)(ws + 393728); // -> 655872
  unsigned long long* best2   = (unsigned long long*)(ws + 655872); // -> 918016
  int*                compG   = (int*)(ws + 918016);                // -> 1049088
  int*                comp2g  = (int*)(ws + 1049088);               // -> 1180160
  int*                ecntG   = (int*)(ws + 1180160);               // -> 1180416
  int*                cntG    = (int*)(ws + 1180416);               // -> 1180672
  size_t base = 1181696;

  // per batch (2 matrices): D 2MB + Hi 1MB + Lo 1MB + Dc 256KB
  size_t perBatch = 2ull * (NN2 * sizeof(float) + 2ull * NN2 * 2 + 16384 * 8);
  size_t dcap = (ws_size > base) ? (ws_size - base) : 0;
  int cb = (int)(dcap / perBatch);
  if (cb > NB) cb = NB;
  if (cb < 1) cb = 1;
  int nmc = 2 * cb;

  float* Dreg = (float*)(ws + base);
  unsigned short* Hi = (unsigned short*)(ws + base + (size_t)nmc * NN2 * sizeof(float));
  unsigned short* Lo = Hi + (size_t)nmc * NN2;
  unsigned long long* DcG = (unsigned long long*)(Lo + (size_t)nmc * NN2);

  hipMemsetAsync(d_out, 0, sizeof(float), stream);
  hipMemsetAsync(maxBits, 0, 64 * sizeof(unsigned), stream);

  for (int b0 = 0; b0 < NB; b0 += cb) {
    int nb = (NB - b0 < cb) ? (NB - b0) : cb;
    int nm = 2 * nb, m0 = 2 * b0;
    // best1 and best2 are contiguous: one 0xFF memset covers both
    hipMemsetAsync(best1 + (size_t)m0 * NN, 0xFF, (size_t)nm * NN * 16, stream);
    hipMemsetAsync(DcG, 0xFF, (size_t)nm * 16384 * 8, stream);
    split_kernel<<<nm * 256, 256, 0, stream>>>(model, labels, Hi, Lo, sq, m0);
    gemm_dist<<<10 * nm, 256, 0, stream>>>(Hi, Lo, sq, Dreg, maxBits, best1, m0, nm);
    hook1_kernel<<<nm, 512, 0, stream>>>(best1, compG, eo, ecntG, m0);
    scan2_kernel<<<dim3(8, nm), 512, 0, stream>>>(Dreg, compG, best2, m0);
    hook2_kernel<<<nm, 512, 0, stream>>>(best2, compG, comp2g, eo, ecntG, cntG, m0);
    contract_kernel<<<dim3(4, nm), 512, 0, stream>>>(Dreg, comp2g, DcG, m0);
    finish_kernel<<<nm, 1024, 0, stream>>>(Dreg, DcG, comp2g, cntG, eo, ecntG,
                                           maxBits, out, m0);
  }
}